// Round 6
// baseline (190.533 us; speedup 1.0000x reference)
//
#include <hip/hip_runtime.h>
#include <hip/hip_bf16.h>

#define BATCH  2
#define SEQ    2048
#define DMODEL 1024
#define NHEAD  16
#define DHEAD  64
#define NTOK   (BATCH * SEQ)

using f32x4 = __attribute__((ext_vector_type(4))) float;
using s16x4 = __attribute__((ext_vector_type(4))) short;
using s16x8 = __attribute__((ext_vector_type(8))) short;

__device__ __forceinline__ short f2bf(float f) {
  __hip_bfloat16 h = __float2bfloat16(f);   // RNE; backend emits cvt_pk pairs
  return *(short*)&h;
}

__device__ __forceinline__ void gload_lds16(const short* g, short* l) {
  __builtin_amdgcn_global_load_lds(
      (const __attribute__((address_space(1))) void*)g,
      (__attribute__((address_space(3))) void*)l, 16, 0, 0);
}

// ---------------------------------------------------------------------------
// Transpose + cast all 4 weights: W[k][n] fp32 -> Wt[n][k] bf16
// ---------------------------------------------------------------------------
__global__ __launch_bounds__(256) void wtrans_kernel(
    const float* __restrict__ Wq, const float* __restrict__ Wk,
    const float* __restrict__ Wv, const float* __restrict__ Wo,
    short* __restrict__ Wt) {
  __shared__ short tile[64][72];
  const float* W = blockIdx.z == 0 ? Wq : blockIdx.z == 1 ? Wk
                 : blockIdx.z == 2 ? Wv : Wo;
  short* out = Wt + (size_t)blockIdx.z * DMODEL * DMODEL;
  int k0 = blockIdx.x * 64, n0 = blockIdx.y * 64;
  int t = threadIdx.x;
#pragma unroll
  for (int i = 0; i < 4; ++i) {
    int idx = t + i * 256;
    int row = idx >> 4, c4 = idx & 15;
    f32x4 v = *(const f32x4*)(W + (size_t)(k0 + row) * DMODEL + n0 + c4 * 4);
    s16x4 p;
    p[0] = f2bf(v[0]); p[1] = f2bf(v[1]); p[2] = f2bf(v[2]); p[3] = f2bf(v[3]);
    *(s16x4*)&tile[row][c4 * 4] = p;
  }
  __syncthreads();
#pragma unroll
  for (int i = 0; i < 2; ++i) {
    int idx = t + i * 256;
    int nrow = idx >> 3, c8 = idx & 7;
    s16x8 p;
#pragma unroll
    for (int j = 0; j < 8; ++j) p[j] = tile[c8 * 8 + j][nrow];
    *(s16x8*)(out + (size_t)(n0 + nrow) * DMODEL + k0 + c8 * 8) = p;
  }
}

// ---------------------------------------------------------------------------
// Pack mask int32 -> bit words: Mp[b*SEQ+q][kt] bit j = mask[b][q][kt*64+j]
// ---------------------------------------------------------------------------
__global__ __launch_bounds__(256) void mpack_kernel(
    const int* __restrict__ mask, unsigned long long* __restrict__ Mp) {
  const int total_words = BATCH * SEQ * (SEQ / 64);   // 131072
  int lane = threadIdx.x & 63;
  int wv = blockIdx.x * 4 + (threadIdx.x >> 6);
  int nw = gridDim.x * 4;
  for (int w = wv; w < total_words; w += nw) {
    int mv = mask[(size_t)w * 64 + lane];
    unsigned long long bits = __ballot(mv != 0);
    if (lane == 0) Mp[w] = bits;
  }
}

// ---------------------------------------------------------------------------
// QKV projection: X fp32 @ Wt^T + b -> bf16.  T3-min pipelined:
// double-buffered LDS, ONE barrier per K-step, next-tile loads in flight
// across MFMA.  Q,K -> [b*H+h][s][d] (Q pre-scaled); V -> [b*H+h][d][s].
// grid (32,8,3), block 256.
// ---------------------------------------------------------------------------
__global__ __launch_bounds__(256) void proj_qkv_kernel(
    const float* __restrict__ Xq, const float* __restrict__ Xk,
    const float* __restrict__ Xv, const short* __restrict__ Wt,
    const float* __restrict__ bq, const float* __restrict__ bk,
    const float* __restrict__ bv, short* __restrict__ QKV) {
  __shared__ short As[2][128 * 32];   // 8KB each, linear
  __shared__ short Bs[2][128 * 32];
  const int sel = blockIdx.z;
  const float* X    = sel == 0 ? Xq : sel == 1 ? Xk : Xv;
  const float* bias = sel == 0 ? bq : sel == 1 ? bk : bv;
  const short* Wsel = Wt + (size_t)sel * DMODEL * DMODEL;
  short* Obuf = QKV + (size_t)sel * ((size_t)BATCH * NHEAD * SEQ * DHEAD);
  const float scale = sel == 0 ? 0.18033688011111793f : 1.0f;  // (1/8)*log2e

  int m0 = blockIdx.x * 128, n0 = blockIdx.y * 128;
  int t = threadIdx.x, wid = t >> 6, lane = t & 63;
  int lr = lane & 15, lg = lane >> 4;
  int wr = wid >> 1, wc = wid & 1;
  f32x4 acc[4][4] = {};

  // fixed per-thread addressing: A rows ar0/ar0+64, col ac0; B glLDS rows
  const int ar0 = t >> 2, ac0 = (t & 3) << 3;
  const float* Arow0 = X + (size_t)(m0 + ar0) * DMODEL + ac0;
  const float* Arow1 = Arow0 + (size_t)64 * DMODEL;
  const int aofs0 = ar0 * 32 + ac0, aofs1 = aofs0 + 64 * 32;
  const short* Brow0 = Wsel + (size_t)(n0 + ar0) * DMODEL + ac0;
  const short* Brow1 = Brow0 + (size_t)64 * DMODEL;
  const int bofs0 = (t & ~63) << 3, bofs1 = bofs0 + 256 * 8;

  f32x4 a00, a01, a10, a11;
#define LOADA(k0s) {                                                          \
    a00 = *(const f32x4*)(Arow0 + (k0s));                                     \
    a01 = *(const f32x4*)(Arow0 + (k0s) + 4);                                 \
    a10 = *(const f32x4*)(Arow1 + (k0s));                                     \
    a11 = *(const f32x4*)(Arow1 + (k0s) + 4); }
#define STAGEB(bufi, k0s) {                                                   \
    gload_lds16(Brow0 + (k0s), &Bs[bufi][0] + bofs0);                         \
    gload_lds16(Brow1 + (k0s), &Bs[bufi][0] + bofs1); }
#define WRITEA(bufi) {                                                        \
    s16x8 p0, p1;                                                             \
    p0[0]=f2bf(a00[0]); p0[1]=f2bf(a00[1]); p0[2]=f2bf(a00[2]); p0[3]=f2bf(a00[3]); \
    p0[4]=f2bf(a01[0]); p0[5]=f2bf(a01[1]); p0[6]=f2bf(a01[2]); p0[7]=f2bf(a01[3]); \
    p1[0]=f2bf(a10[0]); p1[1]=f2bf(a10[1]); p1[2]=f2bf(a10[2]); p1[3]=f2bf(a10[3]); \
    p1[4]=f2bf(a11[0]); p1[5]=f2bf(a11[1]); p1[6]=f2bf(a11[2]); p1[7]=f2bf(a11[3]); \
    *(s16x8*)(&As[bufi][0] + aofs0) = p0;                                     \
    *(s16x8*)(&As[bufi][0] + aofs1) = p1; }

  LOADA(0); STAGEB(0, 0); WRITEA(0);
  __syncthreads();   // drains vmcnt (glLDS) + lgkm (ds_write)

  int cur = 0;
  for (int kt = 0; kt < DMODEL / 32; ++kt) {
    if (kt + 1 < DMODEL / 32) {
      LOADA((kt + 1) * 32);            // fp32 A loads: in flight over MFMA
      STAGEB(cur ^ 1, (kt + 1) * 32);  // glLDS B: in flight over MFMA
    }
    s16x8 afr[4], bfr[4];
#pragma unroll
    for (int mi = 0; mi < 4; ++mi)
      afr[mi] = *(const s16x8*)(&As[cur][0] + (wr * 64 + mi * 16 + lr) * 32 + lg * 8);
#pragma unroll
    for (int ni = 0; ni < 4; ++ni)
      bfr[ni] = *(const s16x8*)(&Bs[cur][0] + (wc * 64 + ni * 16 + lr) * 32 + lg * 8);
    __builtin_amdgcn_s_setprio(1);
#pragma unroll
    for (int mi = 0; mi < 4; ++mi)
#pragma unroll
      for (int ni = 0; ni < 4; ++ni)
        acc[mi][ni] = __builtin_amdgcn_mfma_f32_16x16x32_bf16(
            afr[mi], bfr[ni], acc[mi][ni], 0, 0, 0);
    __builtin_amdgcn_s_setprio(0);
    if (kt + 1 < DMODEL / 32) WRITEA(cur ^ 1);   // waits A-regs only
    __syncthreads();   // drain: glLDS B + A ds_writes visible; reads of cur done
    cur ^= 1;
  }
#undef LOADA
#undef STAGEB
#undef WRITEA

  if (sel == 2) {
    // V^T layout: Obuf[(b*H+h)*64 + d][s]; r spans 4 consecutive s -> b64 store
    int bq_ = m0 >> 11;
    int s0 = (m0 & (SEQ - 1)) + wr * 64 + lg * 4;
#pragma unroll
    for (int mi = 0; mi < 4; ++mi)
#pragma unroll
      for (int ni = 0; ni < 4; ++ni) {
        int n = n0 + wc * 64 + ni * 16 + lr;
        float bv_ = bias[n];
        int h = n >> 6, d = n & 63;
        s16x4 pk;
#pragma unroll
        for (int r = 0; r < 4; ++r) pk[r] = f2bf(acc[mi][ni][r] + bv_);
        *(s16x4*)&Obuf[((size_t)(bq_ * NHEAD + h) * DHEAD + d) * SEQ
                       + s0 + mi * 16] = pk;
      }
  } else {
#pragma unroll
    for (int mi = 0; mi < 4; ++mi)
#pragma unroll
      for (int ni = 0; ni < 4; ++ni) {
        int n = n0 + wc * 64 + ni * 16 + lr;
        float bv_ = bias[n];
        int h = n >> 6, d = n & 63;
#pragma unroll
        for (int r = 0; r < 4; ++r) {
          int m = m0 + wr * 64 + mi * 16 + lg * 4 + r;
          int b = m >> 11, s = m & (SEQ - 1);
          float val = (acc[mi][ni][r] + bv_) * scale;
          Obuf[((size_t)(b * NHEAD + h) * SEQ + s) * DHEAD + d] = f2bf(val);
        }
      }
  }
}

// ---------------------------------------------------------------------------
// Flash attention, swapped QK^T. grid (32, 32), block 256.
// K,V^T staged via global_load_lds (pre-swizzled source), double-buffered,
// ONE barrier per KV-tile (T3-min).  Base-2 softmax domain.
// ---------------------------------------------------------------------------
__global__ __launch_bounds__(256) void attn_kernel(
    const short* __restrict__ Qb, const short* __restrict__ Kb,
    const short* __restrict__ VbT, const unsigned long long* __restrict__ Mp,
    short* __restrict__ Ctx) {
  __shared__ short Ks[2][64 * 64];    // [key][d], 16B-chunk c ^= key&7
  __shared__ short Vt[2][64 * 64];    // [d][key], chunk c ^= d&7
  __shared__ short Ps[4 * 16 * 64];   // per-wave [q][key], chunk c ^= q&7
  int qt = blockIdx.x, bh = blockIdx.y;
  int b = bh >> 4, h = bh & 15;
  int q0 = qt * 64;
  int t = threadIdx.x, wid = t >> 6, lane = t & 63;
  int lr = lane & 15, lg = lane >> 4;
  int lr7 = lr & 7;

  const short* Qrow = Qb + ((size_t)bh * SEQ + q0 + wid * 16 + lr) * DHEAD;
  s16x8 qf[2];
  qf[0] = *(const s16x8*)(Qrow + lg * 8);
  qf[1] = *(const s16x8*)(Qrow + 32 + lg * 8);

  const short* KbB = Kb + (size_t)bh * SEQ * DHEAD;    // [key][d]
  const short* VtB = VbT + (size_t)bh * DHEAD * SEQ;   // [d][key]

  // glLDS: HW dest = wave-uniform base + lane*16B -> row=rbase+(l>>3), c=l&7.
  // Pre-swizzled source chunk gives LDS[row][c] = G[row][c ^ (row&7)].
  const int srow = lane >> 3;
  const int schunk = ((lane & 7) ^ srow) * 8;

  float m_run = -1e30f, l_run = 0.f;   // per-lane, q = lr
  f32x4 o_acc[4] = {};

  const unsigned long long* mrow =
      Mp + ((size_t)b * SEQ + q0 + wid * 16 + lr) * (SEQ / 64);

#define STAGE(bufi, k0s)                                                      \
  {                                                                           \
    _Pragma("unroll")                                                         \
    for (int i = 0; i < 2; ++i) {                                             \
      int rbase = wid * 16 + i * 8;                                           \
      gload_lds16(KbB + (size_t)((k0s) + rbase + srow) * DHEAD + schunk,      \
                  &Ks[bufi][rbase * 64]);                                     \
      gload_lds16(VtB + (size_t)(rbase + srow) * SEQ + (k0s) + schunk,        \
                  &Vt[bufi][rbase * 64]);                                     \
    }                                                                         \
  }

  unsigned long long mw_cur = mrow[0];
  STAGE(0, 0);
  asm volatile("s_waitcnt vmcnt(0)" ::: "memory");
  __syncthreads();

  int cur = 0;
  for (int kt = 0; kt < SEQ / 64; ++kt) {
    unsigned long long mw_next = 0;
    if (kt + 1 < SEQ / 64) {
      STAGE(cur ^ 1, (kt + 1) * 64);   // async, in flight across compute
      mw_next = mrow[kt + 1];
    }
    const short* KsC = Ks[cur];
    const short* VtC = Vt[cur];

    // S^T = K·Q^T : sfr[nf][r] = S[key = nf*16 + lg*4 + r][q = lr]
    f32x4 sfr[4];
    __builtin_amdgcn_s_setprio(1);
#pragma unroll
    for (int nf = 0; nf < 4; ++nf) {
      int row = nf * 16 + lr;
      s16x8 kf0 = *(const s16x8*)&KsC[row * 64 + ((lg ^ lr7) << 3)];
      s16x8 kf1 = *(const s16x8*)&KsC[row * 64 + (((4 + lg) ^ lr7) << 3)];
      f32x4 c = {};
      c = __builtin_amdgcn_mfma_f32_16x16x32_bf16(kf0, qf[0], c, 0, 0, 0);
      c = __builtin_amdgcn_mfma_f32_16x16x32_bf16(kf1, qf[1], c, 0, 0, 0);
      sfr[nf] = c;
    }
    __builtin_amdgcn_s_setprio(0);

    unsigned w0 = (unsigned)(mw_cur >> (lg * 4));
    unsigned w1 = (unsigned)(mw_cur >> (lg * 4 + 32));
#pragma unroll
    for (int nf = 0; nf < 4; ++nf)
#pragma unroll
      for (int r = 0; r < 4; ++r) {
        unsigned bit = (nf < 2) ? (w0 >> (nf * 16 + r)) : (w1 >> ((nf - 2) * 16 + r));
        if (bit & 1u) sfr[nf][r] = -1e30f;
      }
    float tm = fmaxf(fmaxf(fmaxf(sfr[0][0], sfr[0][1]), fmaxf(sfr[0][2], sfr[0][3])),
                     fmaxf(fmaxf(sfr[1][0], sfr[1][1]), fmaxf(sfr[1][2], sfr[1][3])));
    float tm2 = fmaxf(fmaxf(fmaxf(sfr[2][0], sfr[2][1]), fmaxf(sfr[2][2], sfr[2][3])),
                      fmaxf(fmaxf(sfr[3][0], sfr[3][1]), fmaxf(sfr[3][2], sfr[3][3])));
    tm = fmaxf(tm, tm2);
    tm = fmaxf(tm, __shfl_xor(tm, 16, 64));
    tm = fmaxf(tm, __shfl_xor(tm, 32, 64));

    bool small = __all(tm <= m_run + 8.0f);
    if (!small) {
      float mnew = fmaxf(m_run, tm);
      float scl = __builtin_amdgcn_exp2f(m_run - mnew);
      m_run = mnew;
      l_run *= scl;
      float scl_o[4];
#pragma unroll
      for (int r = 0; r < 4; ++r) scl_o[r] = __shfl(scl, lg * 4 + r, 64);
#pragma unroll
      for (int nf = 0; nf < 4; ++nf)
#pragma unroll
        for (int r = 0; r < 4; ++r) o_acc[nf][r] *= scl_o[r];
    }
    float ps4[4];
#pragma unroll
    for (int nf = 0; nf < 4; ++nf) {
#pragma unroll
      for (int r = 0; r < 4; ++r)
        sfr[nf][r] = __builtin_amdgcn_exp2f(sfr[nf][r] - m_run);
      ps4[nf] = (sfr[nf][0] + sfr[nf][1]) + (sfr[nf][2] + sfr[nf][3]);
    }
    float ps = (ps4[0] + ps4[1]) + (ps4[2] + ps4[3]);
    ps += __shfl_xor(ps, 16, 64);
    ps += __shfl_xor(ps, 32, 64);
    l_run += ps;

    // P -> LDS (wave-private, swizzled), 4 x ds_write_b64
    int psbase = wid * (16 * 64) + lr * 64;
#pragma unroll
    for (int nf = 0; nf < 4; ++nf) {
      s16x4 pk;
#pragma unroll
      for (int r = 0; r < 4; ++r) pk[r] = f2bf(sfr[nf][r]);
      *(s16x4*)&Ps[psbase + ((((2 * nf + (lg >> 1)) ^ lr7) << 3) | ((lg & 1) << 2))] = pk;
    }
    asm volatile("s_waitcnt lgkmcnt(0)" ::: "memory");
    __builtin_amdgcn_sched_barrier(0);

    // PV: O += P·V
    __builtin_amdgcn_s_setprio(1);
#pragma unroll
    for (int ks = 0; ks < 2; ++ks) {
      s16x8 pf = *(const s16x8*)&Ps[psbase + (((ks * 4 + lg) ^ lr7) << 3)];
#pragma unroll
      for (int nf = 0; nf < 4; ++nf) {
        int d = nf * 16 + lr;
        s16x8 vf = *(const s16x8*)&VtC[d * 64 + (((ks * 4 + lg) ^ lr7) << 3)];
        o_acc[nf] = __builtin_amdgcn_mfma_f32_16x16x32_bf16(pf, vf, o_acc[nf], 0, 0, 0);
      }
    }
    __builtin_amdgcn_s_setprio(0);

    asm volatile("s_waitcnt vmcnt(0)" ::: "memory");  // next tile landed
    __syncthreads();                                  // all waves done w/ cur
    cur ^= 1;
    mw_cur = mw_next;
  }
#undef STAGE
  // epilogue: o_acc[nf][r] is q = lg*4+r, d = nf*16+lr
  float l_o[4];
#pragma unroll
  for (int r = 0; r < 4; ++r) l_o[r] = __shfl(l_run, lg * 4 + r, 64);
#pragma unroll
  for (int nf = 0; nf < 4; ++nf)
#pragma unroll
    for (int r = 0; r < 4; ++r) {
      int srow_ = q0 + wid * 16 + lg * 4 + r;
      float val = o_acc[nf][r] / l_o[r];
      Ctx[((size_t)b * SEQ + srow_) * DMODEL + h * DHEAD + nf * 16 + lr] = f2bf(val);
    }
}

// ---------------------------------------------------------------------------
// Output projection: ctx bf16 @ Wo + bo -> fp32 out.  T3-min pipelined,
// both operands via global_load_lds, 1 barrier/K-step.  grid (32,8).
// ---------------------------------------------------------------------------
__global__ __launch_bounds__(256) void proj_out_kernel(
    const short* __restrict__ Ctx, const short* __restrict__ Wot,
    const float* __restrict__ bo, float* __restrict__ Out) {
  __shared__ short As[2][128 * 32];
  __shared__ short Bs[2][128 * 32];
  int m0 = blockIdx.x * 128, n0 = blockIdx.y * 128;
  int t = threadIdx.x, wid = t >> 6, lane = t & 63;
  int lr = lane & 15, lg = lane >> 4;
  int wr = wid >> 1, wc = wid & 1;
  f32x4 acc[4][4] = {};

  const int gr0 = t >> 2, gc0 = (t & 3) << 3;
  const short* Actx0 = Ctx + (size_t)(m0 + gr0) * DMODEL + gc0;
  const short* Actx1 = Actx0 + (size_t)64 * DMODEL;
  const short* Bwo0 = Wot + (size_t)(n0 + gr0) * DMODEL + gc0;
  const short* Bwo1 = Bwo0 + (size_t)64 * DMODEL;
  const int lofs0 = (t & ~63) << 3, lofs1 = lofs0 + 256 * 8;

#define STAGE_PO(bufi, k0s) {                                                 \
    gload_lds16(Actx0 + (k0s), &As[bufi][0] + lofs0);                         \
    gload_lds16(Actx1 + (k0s), &As[bufi][0] + lofs1);                         \
    gload_lds16(Bwo0 + (k0s), &Bs[bufi][0] + lofs0);                          \
    gload_lds16(Bwo1 + (k0s), &Bs[bufi][0] + lofs1); }

  STAGE_PO(0, 0);
  __syncthreads();   // implicit vmcnt(0) drain

  int cur = 0;
  for (int kt = 0; kt < DMODEL / 32; ++kt) {
    if (kt + 1 < DMODEL / 32) STAGE_PO(cur ^ 1, (kt + 1) * 32);
    s16x8 afr[4], bfr[4];
#pragma unroll
    for (int mi = 0; mi < 4; ++mi)
      afr[mi] = *(const s16x8*)(&As[cur][0] + (wr * 64 + mi * 16 + lr) * 32 + lg * 8);
#pragma unroll
    for (int ni = 0; ni < 4; ++ni)
      bfr[ni] = *(const s16x8*)(&Bs[cur][0] + (wc * 64 + ni * 16 + lr) * 32 + lg * 8);
    __builtin_amdgcn_s_setprio(1);
#pragma unroll
    for (int mi = 0; mi < 4; ++mi)
#pragma unroll
      for (int ni = 0; ni < 4; ++ni)
        acc[mi][ni] = __builtin_amdgcn_mfma_f32_16x16x32_bf16(
            afr[mi], bfr[ni], acc[mi][ni], 0, 0, 0);
    __builtin_amdgcn_s_setprio(0);
    __syncthreads();   // drains vmcnt: next tile landed; reads of cur done
    cur ^= 1;
  }
#undef STAGE_PO

#pragma unroll
  for (int mi = 0; mi < 4; ++mi)
#pragma unroll
    for (int ni = 0; ni < 4; ++ni) {
      int n = n0 + wc * 64 + ni * 16 + lr;
      float bv_ = bo[n];
#pragma unroll
      for (int r = 0; r < 4; ++r) {
        int m = m0 + wr * 64 + mi * 16 + lg * 4 + r;
        Out[(size_t)m * DMODEL + n] = acc[mi][ni][r] + bv_;
      }
    }
}

// ---------------------------------------------------------------------------
extern "C" void kernel_launch(void* const* d_in, const int* in_sizes, int n_in,
                              void* d_out, int out_size, void* d_ws, size_t ws_size,
                              hipStream_t stream) {
  const float* key_in   = (const float*)d_in[0];
  const float* value_in = (const float*)d_in[1];
  const float* query_in = (const float*)d_in[2];
  const int*   mask     = (const int*)d_in[3];
  const float* Wq = (const float*)d_in[4];
  const float* bq = (const float*)d_in[5];
  const float* Wk = (const float*)d_in[6];
  const float* bk = (const float*)d_in[7];
  const float* Wv = (const float*)d_in[8];
  const float* bv = (const float*)d_in[9];
  const float* Wo = (const float*)d_in[10];
  const float* bo = (const float*)d_in[11];
  float* out = (float*)d_out;

  short* ws = (short*)d_ws;
  const size_t WSZ   = (size_t)DMODEL * DMODEL;
  const size_t QKVSZ = (size_t)BATCH * NHEAD * SEQ * DHEAD;
  short* Wt  = ws;                         // [4][1024][1024] bf16
  short* QKV = ws + 4 * WSZ;
  short* Qb  = QKV;                        // [bh][s][d]
  short* Kb  = QKV + QKVSZ;                // [bh][s][d]
  short* VbT = QKV + 2 * QKVSZ;            // [bh][d][s]  (pre-transposed)
  short* Ctx = QKV + 3 * QKVSZ;
  // Mp overlays the Wq-transposed region (1 MB < 2 MB), written AFTER
  // proj_qkv has consumed Wt[0] (stream-serialized).
  unsigned long long* Mp = (unsigned long long*)ws;

  wtrans_kernel<<<dim3(16, 16, 4), 256, 0, stream>>>(Wq, Wk, Wv, Wo, Wt);
  proj_qkv_kernel<<<dim3(32, 8, 3), 256, 0, stream>>>(
      query_in, key_in, value_in, Wt, bq, bk, bv, QKV);
  mpack_kernel<<<dim3(1024), 256, 0, stream>>>(mask, Mp);
  attn_kernel<<<dim3(32, 32), 256, 0, stream>>>(Qb, Kb, VbT, Mp, Ctx);
  proj_out_kernel<<<dim3(32, 8), 256, 0, stream>>>(Ctx, Wt + 3 * WSZ, bo, out);
}

// Round 7
// 188.995 us; speedup vs baseline: 1.0081x; 1.0081x over previous
//
#include <hip/hip_runtime.h>
#include <hip/hip_bf16.h>

#define BATCH  2
#define SEQ    2048
#define DMODEL 1024
#define NHEAD  16
#define DHEAD  64
#define NTOK   (BATCH * SEQ)

using f32x4 = __attribute__((ext_vector_type(4))) float;
using s16x4 = __attribute__((ext_vector_type(4))) short;
using s16x8 = __attribute__((ext_vector_type(8))) short;

__device__ __forceinline__ short f2bf(float f) {
  __hip_bfloat16 h = __float2bfloat16(f);   // RNE; backend emits cvt_pk pairs
  return *(short*)&h;
}

__device__ __forceinline__ void gload_lds16(const short* g, short* l) {
  __builtin_amdgcn_global_load_lds(
      (const __attribute__((address_space(1))) void*)g,
      (__attribute__((address_space(3))) void*)l, 16, 0, 0);
}

// ---------------------------------------------------------------------------
// Transpose + cast all 4 weights: W[k][n] fp32 -> Wt[n][k] bf16
// ---------------------------------------------------------------------------
__global__ __launch_bounds__(256) void wtrans_kernel(
    const float* __restrict__ Wq, const float* __restrict__ Wk,
    const float* __restrict__ Wv, const float* __restrict__ Wo,
    short* __restrict__ Wt) {
  __shared__ short tile[64][72];
  const float* W = blockIdx.z == 0 ? Wq : blockIdx.z == 1 ? Wk
                 : blockIdx.z == 2 ? Wv : Wo;
  short* out = Wt + (size_t)blockIdx.z * DMODEL * DMODEL;
  int k0 = blockIdx.x * 64, n0 = blockIdx.y * 64;
  int t = threadIdx.x;
#pragma unroll
  for (int i = 0; i < 4; ++i) {
    int idx = t + i * 256;
    int row = idx >> 4, c4 = idx & 15;
    f32x4 v = *(const f32x4*)(W + (size_t)(k0 + row) * DMODEL + n0 + c4 * 4);
    s16x4 p;
    p[0] = f2bf(v[0]); p[1] = f2bf(v[1]); p[2] = f2bf(v[2]); p[3] = f2bf(v[3]);
    *(s16x4*)&tile[row][c4 * 4] = p;
  }
  __syncthreads();
#pragma unroll
  for (int i = 0; i < 2; ++i) {
    int idx = t + i * 256;
    int nrow = idx >> 3, c8 = idx & 7;
    s16x8 p;
#pragma unroll
    for (int j = 0; j < 8; ++j) p[j] = tile[c8 * 8 + j][nrow];
    *(s16x8*)(out + (size_t)(n0 + nrow) * DMODEL + k0 + c8 * 8) = p;
  }
}

// ---------------------------------------------------------------------------
// Cast activations fp32 -> bf16: Xb[sel][tok][d].  grid (2048, 3), block 256.
// ---------------------------------------------------------------------------
__global__ __launch_bounds__(256) void xcast_kernel(
    const float* __restrict__ Xq, const float* __restrict__ Xk,
    const float* __restrict__ Xv, short* __restrict__ Xb) {
  int sel = blockIdx.y;
  const float* src = sel == 0 ? Xq : sel == 1 ? Xk : Xv;
  size_t off = ((size_t)blockIdx.x * 256 + threadIdx.x) * 8;
  f32x4 v0 = *(const f32x4*)(src + off);
  f32x4 v1 = *(const f32x4*)(src + off + 4);
  s16x8 p;
  p[0] = f2bf(v0[0]); p[1] = f2bf(v0[1]); p[2] = f2bf(v0[2]); p[3] = f2bf(v0[3]);
  p[4] = f2bf(v1[0]); p[5] = f2bf(v1[1]); p[6] = f2bf(v1[2]); p[7] = f2bf(v1[3]);
  *(s16x8*)(Xb + (size_t)sel * NTOK * DMODEL + off) = p;
}

// ---------------------------------------------------------------------------
// Pack mask int32 -> bit words: Mp[b*SEQ+q][kt] bit j = mask[b][q][kt*64+j]
// ---------------------------------------------------------------------------
__global__ __launch_bounds__(256) void mpack_kernel(
    const int* __restrict__ mask, unsigned long long* __restrict__ Mp) {
  const int total_words = BATCH * SEQ * (SEQ / 64);   // 131072
  int lane = threadIdx.x & 63;
  int wv = blockIdx.x * 4 + (threadIdx.x >> 6);
  int nw = gridDim.x * 4;
  for (int w = wv; w < total_words; w += nw) {
    int mv = mask[(size_t)w * 64 + lane];
    unsigned long long bits = __ballot(mv != 0);
    if (lane == 0) Mp[w] = bits;
  }
}

// ---------------------------------------------------------------------------
// QKV projection: Xb bf16 @ Wt^T + b -> bf16.  Pure glLDS both operands,
// double-buffered, 1 barrier/K-step.  XCD-swizzled grid: 768 = 8 XCDs x 96;
// within an XCD: 12 m-panels x all 8 n-blocks (A panel L2-shared 8x,
// B strip L2-shared 12x).  Q,K -> [bh][s][d] (Q pre-scaled); V -> [bh][d][s].
// grid 768 (1D), block 256.
// ---------------------------------------------------------------------------
__global__ __launch_bounds__(256) void proj_qkv_kernel(
    const short* __restrict__ Xb, const short* __restrict__ Wt,
    const float* __restrict__ bq, const float* __restrict__ bk,
    const float* __restrict__ bv, short* __restrict__ QKV) {
  __shared__ short As[2][128 * 32];   // 8KB each, linear
  __shared__ short Bs[2][128 * 32];
  // bijective XCD swizzle: 96 consecutive orig ids per XCD
  int wg = blockIdx.x;
  int orig = (wg & 7) * 96 + (wg >> 3);
  int sel = orig >> 8;                 // 0..2
  int rem = orig & 255;
  int mx = rem >> 3, ny = rem & 7;     // mx 0..31, ny 0..7

  const short* X    = Xb + (size_t)sel * NTOK * DMODEL;
  const float* bias = sel == 0 ? bq : sel == 1 ? bk : bv;
  const short* Wsel = Wt + (size_t)sel * DMODEL * DMODEL;
  short* Obuf = QKV + (size_t)sel * ((size_t)BATCH * NHEAD * SEQ * DHEAD);
  const float scale = sel == 0 ? 0.18033688011111793f : 1.0f;  // (1/8)*log2e

  int m0 = mx * 128, n0 = ny * 128;
  int t = threadIdx.x, wid = t >> 6, lane = t & 63;
  int lr = lane & 15, lg = lane >> 4;
  int wr = wid >> 1, wc = wid & 1;
  f32x4 acc[4][4] = {};

  const int gr0 = t >> 2, gc0 = (t & 3) << 3;
  const short* Ax0 = X + (size_t)(m0 + gr0) * DMODEL + gc0;
  const short* Ax1 = Ax0 + (size_t)64 * DMODEL;
  const short* Bw0 = Wsel + (size_t)(n0 + gr0) * DMODEL + gc0;
  const short* Bw1 = Bw0 + (size_t)64 * DMODEL;
  const int lofs0 = (t & ~63) << 3, lofs1 = lofs0 + 256 * 8;

#define STAGEQ(bufi, k0s) {                                                   \
    gload_lds16(Ax0 + (k0s), &As[bufi][0] + lofs0);                           \
    gload_lds16(Ax1 + (k0s), &As[bufi][0] + lofs1);                           \
    gload_lds16(Bw0 + (k0s), &Bs[bufi][0] + lofs0);                           \
    gload_lds16(Bw1 + (k0s), &Bs[bufi][0] + lofs1); }

  STAGEQ(0, 0);
  __syncthreads();   // implicit vmcnt(0) drain

  int cur = 0;
  for (int kt = 0; kt < DMODEL / 32; ++kt) {
    if (kt + 1 < DMODEL / 32) STAGEQ(cur ^ 1, (kt + 1) * 32);
    s16x8 afr[4], bfr[4];
#pragma unroll
    for (int mi = 0; mi < 4; ++mi)
      afr[mi] = *(const s16x8*)(&As[cur][0] + (wr * 64 + mi * 16 + lr) * 32 + lg * 8);
#pragma unroll
    for (int ni = 0; ni < 4; ++ni)
      bfr[ni] = *(const s16x8*)(&Bs[cur][0] + (wc * 64 + ni * 16 + lr) * 32 + lg * 8);
    __builtin_amdgcn_s_setprio(1);
#pragma unroll
    for (int mi = 0; mi < 4; ++mi)
#pragma unroll
      for (int ni = 0; ni < 4; ++ni)
        acc[mi][ni] = __builtin_amdgcn_mfma_f32_16x16x32_bf16(
            afr[mi], bfr[ni], acc[mi][ni], 0, 0, 0);
    __builtin_amdgcn_s_setprio(0);
    __syncthreads();   // drains vmcnt: next tile landed; reads of cur done
    cur ^= 1;
  }
#undef STAGEQ

  if (sel == 2) {
    // V^T layout: Obuf[(b*H+h)*64 + d][s]; r spans 4 consecutive s -> b64 store
    int bq_ = m0 >> 11;
    int s0 = (m0 & (SEQ - 1)) + wr * 64 + lg * 4;
#pragma unroll
    for (int mi = 0; mi < 4; ++mi)
#pragma unroll
      for (int ni = 0; ni < 4; ++ni) {
        int n = n0 + wc * 64 + ni * 16 + lr;
        float bv_ = bias[n];
        int h = n >> 6, d = n & 63;
        s16x4 pk;
#pragma unroll
        for (int r = 0; r < 4; ++r) pk[r] = f2bf(acc[mi][ni][r] + bv_);
        *(s16x4*)&Obuf[((size_t)(bq_ * NHEAD + h) * DHEAD + d) * SEQ
                       + s0 + mi * 16] = pk;
      }
  } else {
#pragma unroll
    for (int mi = 0; mi < 4; ++mi)
#pragma unroll
      for (int ni = 0; ni < 4; ++ni) {
        int n = n0 + wc * 64 + ni * 16 + lr;
        float bv_ = bias[n];
        int h = n >> 6, d = n & 63;
#pragma unroll
        for (int r = 0; r < 4; ++r) {
          int m = m0 + wr * 64 + mi * 16 + lg * 4 + r;
          int b = m >> 11, s = m & (SEQ - 1);
          float val = (acc[mi][ni][r] + bv_) * scale;
          Obuf[((size_t)(b * NHEAD + h) * SEQ + s) * DHEAD + d] = f2bf(val);
        }
      }
  }
}

// ---------------------------------------------------------------------------
// Flash attention, swapped QK^T. grid 1024 (1D, XCD-swizzled: 4 bh per XCD
// so K/V panels stay L2-local), block 256.
// K,V^T staged via global_load_lds (pre-swizzled source), double-buffered,
// ONE barrier per KV-tile.  Base-2 softmax domain.
// ---------------------------------------------------------------------------
__global__ __launch_bounds__(256) void attn_kernel(
    const short* __restrict__ Qb, const short* __restrict__ Kb,
    const short* __restrict__ VbT, const unsigned long long* __restrict__ Mp,
    short* __restrict__ Ctx) {
  __shared__ short Ks[2][64 * 64];    // [key][d], 16B-chunk c ^= key&7
  __shared__ short Vt[2][64 * 64];    // [d][key], chunk c ^= d&7
  __shared__ short Ps[4 * 16 * 64];   // per-wave [q][key], chunk c ^= q&7
  int wg = blockIdx.x;
  int orig = (wg & 7) * 128 + (wg >> 3);   // bijective: 1024 = 8 x 128
  int bh = orig >> 5, qt = orig & 31;
  int b = bh >> 4, h = bh & 15;
  int q0 = qt * 64;
  int t = threadIdx.x, wid = t >> 6, lane = t & 63;
  int lr = lane & 15, lg = lane >> 4;
  int lr7 = lr & 7;

  const short* Qrow = Qb + ((size_t)bh * SEQ + q0 + wid * 16 + lr) * DHEAD;
  s16x8 qf[2];
  qf[0] = *(const s16x8*)(Qrow + lg * 8);
  qf[1] = *(const s16x8*)(Qrow + 32 + lg * 8);

  const short* KbB = Kb + (size_t)bh * SEQ * DHEAD;    // [key][d]
  const short* VtB = VbT + (size_t)bh * DHEAD * SEQ;   // [d][key]

  // glLDS: HW dest = wave-uniform base + lane*16B -> row=rbase+(l>>3), c=l&7.
  // Pre-swizzled source chunk gives LDS[row][c] = G[row][c ^ (row&7)].
  const int srow = lane >> 3;
  const int schunk = ((lane & 7) ^ srow) * 8;

  float m_run = -1e30f, l_run = 0.f;   // per-lane, q = lr
  f32x4 o_acc[4] = {};

  const unsigned long long* mrow =
      Mp + ((size_t)b * SEQ + q0 + wid * 16 + lr) * (SEQ / 64);

#define STAGE(bufi, k0s)                                                      \
  {                                                                           \
    _Pragma("unroll")                                                         \
    for (int i = 0; i < 2; ++i) {                                             \
      int rbase = wid * 16 + i * 8;                                           \
      gload_lds16(KbB + (size_t)((k0s) + rbase + srow) * DHEAD + schunk,      \
                  &Ks[bufi][rbase * 64]);                                     \
      gload_lds16(VtB + (size_t)(rbase + srow) * SEQ + (k0s) + schunk,        \
                  &Vt[bufi][rbase * 64]);                                     \
    }                                                                         \
  }

  unsigned long long mw_cur = mrow[0];
  STAGE(0, 0);
  asm volatile("s_waitcnt vmcnt(0)" ::: "memory");
  __syncthreads();

  int cur = 0;
  for (int kt = 0; kt < SEQ / 64; ++kt) {
    unsigned long long mw_next = 0;
    if (kt + 1 < SEQ / 64) {
      STAGE(cur ^ 1, (kt + 1) * 64);   // async, in flight across compute
      mw_next = mrow[kt + 1];
    }
    const short* KsC = Ks[cur];
    const short* VtC = Vt[cur];

    // S^T = K·Q^T : sfr[nf][r] = S[key = nf*16 + lg*4 + r][q = lr]
    f32x4 sfr[4];
    __builtin_amdgcn_s_setprio(1);
#pragma unroll
    for (int nf = 0; nf < 4; ++nf) {
      int row = nf * 16 + lr;
      s16x8 kf0 = *(const s16x8*)&KsC[row * 64 + ((lg ^ lr7) << 3)];
      s16x8 kf1 = *(const s16x8*)&KsC[row * 64 + (((4 + lg) ^ lr7) << 3)];
      f32x4 c = {};
      c = __builtin_amdgcn_mfma_f32_16x16x32_bf16(kf0, qf[0], c, 0, 0, 0);
      c = __builtin_amdgcn_mfma_f32_16x16x32_bf16(kf1, qf[1], c, 0, 0, 0);
      sfr[nf] = c;
    }
    __builtin_amdgcn_s_setprio(0);

    unsigned w0 = (unsigned)(mw_cur >> (lg * 4));
    unsigned w1 = (unsigned)(mw_cur >> (lg * 4 + 32));
#pragma unroll
    for (int nf = 0; nf < 4; ++nf)
#pragma unroll
      for (int r = 0; r < 4; ++r) {
        unsigned bit = (nf < 2) ? (w0 >> (nf * 16 + r)) : (w1 >> ((nf - 2) * 16 + r));
        if (bit & 1u) sfr[nf][r] = -1e30f;
      }
    float tm = fmaxf(fmaxf(fmaxf(sfr[0][0], sfr[0][1]), fmaxf(sfr[0][2], sfr[0][3])),
                     fmaxf(fmaxf(sfr[1][0], sfr[1][1]), fmaxf(sfr[1][2], sfr[1][3])));
    float tm2 = fmaxf(fmaxf(fmaxf(sfr[2][0], sfr[2][1]), fmaxf(sfr[2][2], sfr[2][3])),
                      fmaxf(fmaxf(sfr[3][0], sfr[3][1]), fmaxf(sfr[3][2], sfr[3][3])));
    tm = fmaxf(tm, tm2);
    tm = fmaxf(tm, __shfl_xor(tm, 16, 64));
    tm = fmaxf(tm, __shfl_xor(tm, 32, 64));

    bool small = __all(tm <= m_run + 8.0f);
    if (!small) {
      float mnew = fmaxf(m_run, tm);
      float scl = __builtin_amdgcn_exp2f(m_run - mnew);
      m_run = mnew;
      l_run *= scl;
      float scl_o[4];
#pragma unroll
      for (int r = 0; r < 4; ++r) scl_o[r] = __shfl(scl, lg * 4 + r, 64);
#pragma unroll
      for (int nf = 0; nf < 4; ++nf)
#pragma unroll
        for (int r = 0; r < 4; ++r) o_acc[nf][r] *= scl_o[r];
    }
    float ps4[4];
#pragma unroll
    for (int nf = 0; nf < 4; ++nf) {
#pragma unroll
      for (int r = 0; r < 4; ++r)
        sfr[nf][r] = __builtin_amdgcn_exp2f(sfr[nf][r] - m_run);
      ps4[nf] = (sfr[nf][0] + sfr[nf][1]) + (sfr[nf][2] + sfr[nf][3]);
    }
    float ps = (ps4[0] + ps4[1]) + (ps4[2] + ps4[3]);
    ps += __shfl_xor(ps, 16, 64);
    ps += __shfl_xor(ps, 32, 64);
    l_run += ps;

    // P -> LDS (wave-private, swizzled), 4 x ds_write_b64
    int psbase = wid * (16 * 64) + lr * 64;
#pragma unroll
    for (int nf = 0; nf < 4; ++nf) {
      s16x4 pk;
#pragma unroll
      for (int r = 0; r < 4; ++r) pk[r] = f2bf(sfr[nf][r]);
      *(s16x4*)&Ps[psbase + ((((2 * nf + (lg >> 1)) ^ lr7) << 3) | ((lg & 1) << 2))] = pk;
    }
    asm volatile("s_waitcnt lgkmcnt(0)" ::: "memory");
    __builtin_amdgcn_sched_barrier(0);

    // PV: O += P·V
    __builtin_amdgcn_s_setprio(1);
#pragma unroll
    for (int ks = 0; ks < 2; ++ks) {
      s16x8 pf = *(const s16x8*)&Ps[psbase + (((ks * 4 + lg) ^ lr7) << 3)];
#pragma unroll
      for (int nf = 0; nf < 4; ++nf) {
        int d = nf * 16 + lr;
        s16x8 vf = *(const s16x8*)&VtC[d * 64 + (((ks * 4 + lg) ^ lr7) << 3)];
        o_acc[nf] = __builtin_amdgcn_mfma_f32_16x16x32_bf16(pf, vf, o_acc[nf], 0, 0, 0);
      }
    }
    __builtin_amdgcn_s_setprio(0);

    asm volatile("s_waitcnt vmcnt(0)" ::: "memory");  // next tile landed
    __syncthreads();                                  // all waves done w/ cur
    cur ^= 1;
    mw_cur = mw_next;
  }
#undef STAGE
  // epilogue: o_acc[nf][r] is q = lg*4+r, d = nf*16+lr
  float l_o[4];
#pragma unroll
  for (int r = 0; r < 4; ++r) l_o[r] = __shfl(l_run, lg * 4 + r, 64);
#pragma unroll
  for (int nf = 0; nf < 4; ++nf)
#pragma unroll
    for (int r = 0; r < 4; ++r) {
      int srow_ = q0 + wid * 16 + lg * 4 + r;
      float val = o_acc[nf][r] / l_o[r];
      Ctx[((size_t)b * SEQ + srow_) * DMODEL + h * DHEAD + nf * 16 + lr] = f2bf(val);
    }
}

// ---------------------------------------------------------------------------
// Output projection: ctx bf16 @ Wo + bo -> fp32 out.  Pure glLDS,
// double-buffered, 1 barrier/K-step, XCD-swizzled (256 = 8 x 32).
// grid 256 (1D), block 256.
// ---------------------------------------------------------------------------
__global__ __launch_bounds__(256) void proj_out_kernel(
    const short* __restrict__ Ctx, const short* __restrict__ Wot,
    const float* __restrict__ bo, float* __restrict__ Out) {
  __shared__ short As[2][128 * 32];
  __shared__ short Bs[2][128 * 32];
  int wg = blockIdx.x;
  int orig = (wg & 7) * 32 + (wg >> 3);    // bijective: 256 = 8 x 32
  int mx = orig >> 3, ny = orig & 7;
  int m0 = mx * 128, n0 = ny * 128;
  int t = threadIdx.x, wid = t >> 6, lane = t & 63;
  int lr = lane & 15, lg = lane >> 4;
  int wr = wid >> 1, wc = wid & 1;
  f32x4 acc[4][4] = {};

  const int gr0 = t >> 2, gc0 = (t & 3) << 3;
  const short* Actx0 = Ctx + (size_t)(m0 + gr0) * DMODEL + gc0;
  const short* Actx1 = Actx0 + (size_t)64 * DMODEL;
  const short* Bwo0 = Wot + (size_t)(n0 + gr0) * DMODEL + gc0;
  const short* Bwo1 = Bwo0 + (size_t)64 * DMODEL;
  const int lofs0 = (t & ~63) << 3, lofs1 = lofs0 + 256 * 8;

#define STAGE_PO(bufi, k0s) {                                                 \
    gload_lds16(Actx0 + (k0s), &As[bufi][0] + lofs0);                         \
    gload_lds16(Actx1 + (k0s), &As[bufi][0] + lofs1);                         \
    gload_lds16(Bwo0 + (k0s), &Bs[bufi][0] + lofs0);                          \
    gload_lds16(Bwo1 + (k0s), &Bs[bufi][0] + lofs1); }

  STAGE_PO(0, 0);
  __syncthreads();   // implicit vmcnt(0) drain

  int cur = 0;
  for (int kt = 0; kt < DMODEL / 32; ++kt) {
    if (kt + 1 < DMODEL / 32) STAGE_PO(cur ^ 1, (kt + 1) * 32);
    s16x8 afr[4], bfr[4];
#pragma unroll
    for (int mi = 0; mi < 4; ++mi)
      afr[mi] = *(const s16x8*)(&As[cur][0] + (wr * 64 + mi * 16 + lr) * 32 + lg * 8);
#pragma unroll
    for (int ni = 0; ni < 4; ++ni)
      bfr[ni] = *(const s16x8*)(&Bs[cur][0] + (wc * 64 + ni * 16 + lr) * 32 + lg * 8);
    __builtin_amdgcn_s_setprio(1);
#pragma unroll
    for (int mi = 0; mi < 4; ++mi)
#pragma unroll
      for (int ni = 0; ni < 4; ++ni)
        acc[mi][ni] = __builtin_amdgcn_mfma_f32_16x16x32_bf16(
            afr[mi], bfr[ni], acc[mi][ni], 0, 0, 0);
    __builtin_amdgcn_s_setprio(0);
    __syncthreads();   // drains vmcnt: next tile landed; reads of cur done
    cur ^= 1;
  }
#undef STAGE_PO

#pragma unroll
  for (int mi = 0; mi < 4; ++mi)
#pragma unroll
    for (int ni = 0; ni < 4; ++ni) {
      int n = n0 + wc * 64 + ni * 16 + lr;
      float bv_ = bo[n];
#pragma unroll
      for (int r = 0; r < 4; ++r) {
        int m = m0 + wr * 64 + mi * 16 + lg * 4 + r;
        Out[(size_t)m * DMODEL + n] = acc[mi][ni][r] + bv_;
      }
    }
}

// ---------------------------------------------------------------------------
extern "C" void kernel_launch(void* const* d_in, const int* in_sizes, int n_in,
                              void* d_out, int out_size, void* d_ws, size_t ws_size,
                              hipStream_t stream) {
  const float* key_in   = (const float*)d_in[0];
  const float* value_in = (const float*)d_in[1];
  const float* query_in = (const float*)d_in[2];
  const int*   mask     = (const int*)d_in[3];
  const float* Wq = (const float*)d_in[4];
  const float* bq = (const float*)d_in[5];
  const float* Wk = (const float*)d_in[6];
  const float* bk = (const float*)d_in[7];
  const float* Wv = (const float*)d_in[8];
  const float* bv = (const float*)d_in[9];
  const float* Wo = (const float*)d_in[10];
  const float* bo = (const float*)d_in[11];
  float* out = (float*)d_out;

  short* ws = (short*)d_ws;
  const size_t WSZ   = (size_t)DMODEL * DMODEL;              // 1M elems
  const size_t QKVSZ = (size_t)BATCH * NHEAD * SEQ * DHEAD;  // 4M elems
  const size_t XSZ   = (size_t)NTOK * DMODEL;                // 4M elems
  short* Wt  = ws;                         // [0, 4M)   4 weights bf16
  short* QKV = ws + 4 * WSZ;               // Q [4M,8M) K [8M,12M) V^T [12M,16M)
  short* Qb  = QKV;
  short* Kb  = QKV + QKVSZ;
  short* VbT = QKV + 2 * QKVSZ;            // [bh][d][s]  (pre-transposed)
  short* Xb  = ws + 4 * WSZ + 3 * QKVSZ;   // [16M, 28M)  bf16 activations
  short* Ctx = Xb;                         // overlays Xb[query]: Xb dead
                                           // before attn writes Ctx (serial)
  // Mp overlays the Wq-transposed region (1 MB < 2 MB), written AFTER
  // proj_qkv has consumed Wt[0] (stream-serialized).
  unsigned long long* Mp = (unsigned long long*)ws;

  wtrans_kernel<<<dim3(16, 16, 4), 256, 0, stream>>>(Wq, Wk, Wv, Wo, Wt);
  xcast_kernel<<<dim3(2048, 3), 256, 0, stream>>>(query_in, key_in, value_in, Xb);
  proj_qkv_kernel<<<dim3(768), 256, 0, stream>>>(Xb, Wt, bq, bk, bv, QKV);
  mpack_kernel<<<dim3(1024), 256, 0, stream>>>(mask, Mp);
  attn_kernel<<<dim3(1024), 256, 0, stream>>>(Qb, Kb, VbT, Mp, Ctx);
  proj_out_kernel<<<dim3(256), 256, 0, stream>>>(Ctx, Wt + 3 * WSZ, bo, out);
}

// Round 9
// 183.907 us; speedup vs baseline: 1.0360x; 1.0277x over previous
//
#include <hip/hip_runtime.h>
#include <hip/hip_bf16.h>

#define BATCH  2
#define SEQ    2048
#define DMODEL 1024
#define NHEAD  16
#define DHEAD  64
#define NTOK   (BATCH * SEQ)

using f32x4  = __attribute__((ext_vector_type(4))) float;
using f32x16 = __attribute__((ext_vector_type(16))) float;
using s16x4  = __attribute__((ext_vector_type(4))) short;
using s16x8  = __attribute__((ext_vector_type(8))) short;

__device__ __forceinline__ short f2bf(float f) {
  __hip_bfloat16 h = __float2bfloat16(f);   // RNE; backend emits cvt_pk pairs
  return *(short*)&h;
}

__device__ __forceinline__ void gload_lds16(const short* g, short* l) {
  __builtin_amdgcn_global_load_lds(
      (const __attribute__((address_space(1))) void*)g,
      (__attribute__((address_space(3))) void*)l, 16, 0, 0);
}

// ---------------------------------------------------------------------------
// Transpose + cast all 4 weights: W[k][n] fp32 -> Wt[n][k] bf16
// ---------------------------------------------------------------------------
__global__ __launch_bounds__(256) void wtrans_kernel(
    const float* __restrict__ Wq, const float* __restrict__ Wk,
    const float* __restrict__ Wv, const float* __restrict__ Wo,
    short* __restrict__ Wt) {
  __shared__ short tile[64][72];
  const float* W = blockIdx.z == 0 ? Wq : blockIdx.z == 1 ? Wk
                 : blockIdx.z == 2 ? Wv : Wo;
  short* out = Wt + (size_t)blockIdx.z * DMODEL * DMODEL;
  int k0 = blockIdx.x * 64, n0 = blockIdx.y * 64;
  int t = threadIdx.x;
#pragma unroll
  for (int i = 0; i < 4; ++i) {
    int idx = t + i * 256;
    int row = idx >> 4, c4 = idx & 15;
    f32x4 v = *(const f32x4*)(W + (size_t)(k0 + row) * DMODEL + n0 + c4 * 4);
    s16x4 p;
    p[0] = f2bf(v[0]); p[1] = f2bf(v[1]); p[2] = f2bf(v[2]); p[3] = f2bf(v[3]);
    *(s16x4*)&tile[row][c4 * 4] = p;
  }
  __syncthreads();
#pragma unroll
  for (int i = 0; i < 2; ++i) {
    int idx = t + i * 256;
    int nrow = idx >> 3, c8 = idx & 7;
    s16x8 p;
#pragma unroll
    for (int j = 0; j < 8; ++j) p[j] = tile[c8 * 8 + j][nrow];
    *(s16x8*)(out + (size_t)(n0 + nrow) * DMODEL + k0 + c8 * 8) = p;
  }
}

// ---------------------------------------------------------------------------
// Cast activations fp32 -> bf16: Xb[sel][tok][d].  grid (2048, 3), block 256.
// ---------------------------------------------------------------------------
__global__ __launch_bounds__(256) void xcast_kernel(
    const float* __restrict__ Xq, const float* __restrict__ Xk,
    const float* __restrict__ Xv, short* __restrict__ Xb) {
  int sel = blockIdx.y;
  const float* src = sel == 0 ? Xq : sel == 1 ? Xk : Xv;
  size_t off = ((size_t)blockIdx.x * 256 + threadIdx.x) * 8;
  f32x4 v0 = *(const f32x4*)(src + off);
  f32x4 v1 = *(const f32x4*)(src + off + 4);
  s16x8 p;
  p[0] = f2bf(v0[0]); p[1] = f2bf(v0[1]); p[2] = f2bf(v0[2]); p[3] = f2bf(v0[3]);
  p[4] = f2bf(v1[0]); p[5] = f2bf(v1[1]); p[6] = f2bf(v1[2]); p[7] = f2bf(v1[3]);
  *(s16x8*)(Xb + (size_t)sel * NTOK * DMODEL + off) = p;
}

// ---------------------------------------------------------------------------
// Pack mask int32 -> bit words: Mp[b*SEQ+q][kt] bit j = mask[b][q][kt*64+j]
// ---------------------------------------------------------------------------
__global__ __launch_bounds__(256) void mpack_kernel(
    const int* __restrict__ mask, unsigned long long* __restrict__ Mp) {
  const int total_words = BATCH * SEQ * (SEQ / 64);   // 131072
  int lane = threadIdx.x & 63;
  int wv = blockIdx.x * 4 + (threadIdx.x >> 6);
  int nw = gridDim.x * 4;
  for (int w = wv; w < total_words; w += nw) {
    int mv = mask[(size_t)w * 64 + lane];
    unsigned long long bits = __ballot(mv != 0);
    if (lane == 0) Mp[w] = bits;
  }
}

// ---------------------------------------------------------------------------
// QKV projection: Xb bf16 @ Wt^T + b -> bf16.  Pure glLDS both operands,
// double-buffered, 1 barrier/K-step, XCD-swizzled (768 = 8 x 96).
// Q,K -> [bh][s][d] (Q pre-scaled); V -> [bh][d][s].  grid 768, block 256.
// ---------------------------------------------------------------------------
__global__ __launch_bounds__(256) void proj_qkv_kernel(
    const short* __restrict__ Xb, const short* __restrict__ Wt,
    const float* __restrict__ bq, const float* __restrict__ bk,
    const float* __restrict__ bv, short* __restrict__ QKV) {
  __shared__ short As[2][128 * 32];   // 8KB each, linear
  __shared__ short Bs[2][128 * 32];
  int wg = blockIdx.x;
  int orig = (wg & 7) * 96 + (wg >> 3);
  int sel = orig >> 8;                 // 0..2
  int rem = orig & 255;
  int mx = rem >> 3, ny = rem & 7;     // mx 0..31, ny 0..7

  const short* X    = Xb + (size_t)sel * NTOK * DMODEL;
  const float* bias = sel == 0 ? bq : sel == 1 ? bk : bv;
  const short* Wsel = Wt + (size_t)sel * DMODEL * DMODEL;
  short* Obuf = QKV + (size_t)sel * ((size_t)BATCH * NHEAD * SEQ * DHEAD);
  const float scale = sel == 0 ? 0.18033688011111793f : 1.0f;  // (1/8)*log2e

  int m0 = mx * 128, n0 = ny * 128;
  int t = threadIdx.x, wid = t >> 6, lane = t & 63;
  int lr = lane & 15, lg = lane >> 4;
  int wr = wid >> 1, wc = wid & 1;
  f32x4 acc[4][4] = {};

  const int gr0 = t >> 2, gc0 = (t & 3) << 3;
  const short* Ax0 = X + (size_t)(m0 + gr0) * DMODEL + gc0;
  const short* Ax1 = Ax0 + (size_t)64 * DMODEL;
  const short* Bw0 = Wsel + (size_t)(n0 + gr0) * DMODEL + gc0;
  const short* Bw1 = Bw0 + (size_t)64 * DMODEL;
  const int lofs0 = (t & ~63) << 3, lofs1 = lofs0 + 256 * 8;

#define STAGEQ(bufi, k0s) {                                                   \
    gload_lds16(Ax0 + (k0s), &As[bufi][0] + lofs0);                           \
    gload_lds16(Ax1 + (k0s), &As[bufi][0] + lofs1);                           \
    gload_lds16(Bw0 + (k0s), &Bs[bufi][0] + lofs0);                           \
    gload_lds16(Bw1 + (k0s), &Bs[bufi][0] + lofs1); }

  STAGEQ(0, 0);
  __syncthreads();   // implicit vmcnt(0) drain

  int cur = 0;
  for (int kt = 0; kt < DMODEL / 32; ++kt) {
    if (kt + 1 < DMODEL / 32) STAGEQ(cur ^ 1, (kt + 1) * 32);
    s16x8 afr[4], bfr[4];
#pragma unroll
    for (int mi = 0; mi < 4; ++mi)
      afr[mi] = *(const s16x8*)(&As[cur][0] + (wr * 64 + mi * 16 + lr) * 32 + lg * 8);
#pragma unroll
    for (int ni = 0; ni < 4; ++ni)
      bfr[ni] = *(const s16x8*)(&Bs[cur][0] + (wc * 64 + ni * 16 + lr) * 32 + lg * 8);
    __builtin_amdgcn_s_setprio(1);
#pragma unroll
    for (int mi = 0; mi < 4; ++mi)
#pragma unroll
      for (int ni = 0; ni < 4; ++ni)
        acc[mi][ni] = __builtin_amdgcn_mfma_f32_16x16x32_bf16(
            afr[mi], bfr[ni], acc[mi][ni], 0, 0, 0);
    __builtin_amdgcn_s_setprio(0);
    __syncthreads();   // drains vmcnt: next tile landed; reads of cur done
    cur ^= 1;
  }
#undef STAGEQ

  if (sel == 2) {
    // V^T layout: Obuf[(b*H+h)*64 + d][s]; r spans 4 consecutive s -> b64 store
    int bq_ = m0 >> 11;
    int s0 = (m0 & (SEQ - 1)) + wr * 64 + lg * 4;
#pragma unroll
    for (int mi = 0; mi < 4; ++mi)
#pragma unroll
      for (int ni = 0; ni < 4; ++ni) {
        int n = n0 + wc * 64 + ni * 16 + lr;
        float bv_ = bias[n];
        int h = n >> 6, d = n & 63;
        s16x4 pk;
#pragma unroll
        for (int r = 0; r < 4; ++r) pk[r] = f2bf(acc[mi][ni][r] + bv_);
        *(s16x4*)&Obuf[((size_t)(bq_ * NHEAD + h) * DHEAD + d) * SEQ
                       + s0 + mi * 16] = pk;
      }
  } else {
#pragma unroll
    for (int mi = 0; mi < 4; ++mi)
#pragma unroll
      for (int ni = 0; ni < 4; ++ni) {
        int n = n0 + wc * 64 + ni * 16 + lr;
        float bv_ = bias[n];
        int h = n >> 6, d = n & 63;
#pragma unroll
        for (int r = 0; r < 4; ++r) {
          int m = m0 + wr * 64 + mi * 16 + lg * 4 + r;
          int b = m >> 11, s = m & (SEQ - 1);
          float val = (acc[mi][ni][r] + bv_) * scale;
          Obuf[((size_t)(b * NHEAD + h) * SEQ + s) * DHEAD + d] = f2bf(val);
        }
      }
  }
}

// ---------------------------------------------------------------------------
// Flash attention, 32x32 swapped QK^T, in-register softmax.  No permlane:
// P stays in native D-layout slots; V is read with the MATCHING interleaved
// key order (two b64 reads per 16-key block) so the k-permutation cancels
// inside the PV MFMA.  Cross-half reduce via __shfl_xor(.,32) (verified).
// Per wave: 32 q-rows; block = 4 waves = 128 q-rows.  grid 512 (8x64 XCD
// swizzle), block 256.  K,V^T via glLDS (pre-swizzled source), dbuf,
// one barrier per KV-tile.  Base-2 softmax domain; defer-max (T13).
// D layout (m74/m101): col=lane&31 (=q), row=(r&3)+8*(r>>2)+4*hi.
// ---------------------------------------------------------------------------
__global__ __launch_bounds__(256) void attn_kernel(
    const short* __restrict__ Qb, const short* __restrict__ Kb,
    const short* __restrict__ VbT, const unsigned long long* __restrict__ Mp,
    short* __restrict__ Ctx) {
  __shared__ short Ks[2][64 * 64];    // [key][d], 16B-chunk c ^= key&7
  __shared__ short Vt[2][64 * 64];    // [d][key], chunk c ^= d&7
  int wg = blockIdx.x;
  int orig = (wg & 7) * 64 + (wg >> 3);    // bijective: 512 = 8 x 64
  int bh = orig >> 4, qt = orig & 15;
  int b = bh >> 4, h = bh & 15;
  int q0 = qt * 128;
  int t = threadIdx.x, wid = t >> 6, lane = t & 63;
  int ql = lane & 31, hi = lane >> 5;
  int qrow = q0 + wid * 32 + ql;

  // Q as MFMA-B fragments: qf[ds] = Q[qrow][ds*16 + hi*8 .. +7]
  const short* Qp = Qb + ((size_t)bh * SEQ + qrow) * DHEAD + hi * 8;
  s16x8 qf[4];
#pragma unroll
  for (int ds = 0; ds < 4; ++ds) qf[ds] = *(const s16x8*)(Qp + ds * 16);

  const short* KbB = Kb + (size_t)bh * SEQ * DHEAD;    // [key][d]
  const short* VtB = VbT + (size_t)bh * DHEAD * SEQ;   // [d][key]

  // glLDS staging (identical swizzle to prior verified rounds)
  const int srow = lane >> 3;
  const int schunk = ((lane & 7) ^ srow) * 8;

  // K read offsets: logical 16B chunk j*2+hi of row ql (swizzled)
  int offK[4];
#pragma unroll
  for (int j = 0; j < 4; ++j)
    offK[j] = ql * 64 + (((j * 2 + hi) ^ (ql & 7)) << 3);
  // V read offsets (b64): keys m*16+4*hi..+3 and m*16+8+4*hi..+3 of row ql
  int offVa[4], offVb[4];
#pragma unroll
  for (int m = 0; m < 4; ++m) {
    offVa[m] = ql * 64 + (((m * 2)     ^ (ql & 7)) << 3) + 4 * hi;
    offVb[m] = ql * 64 + (((m * 2 + 1) ^ (ql & 7)) << 3) + 4 * hi;
  }

  float m_run = -1e30f, l_run = 0.f;   // per-lane, q = ql (dup over hi)
  f32x16 oacc0 = {}, oacc1 = {};       // O[q'=crow(r,hi)][d = ql (+32)]

  const unsigned long long* mrow = Mp + ((size_t)b * SEQ + qrow) * (SEQ / 64);

#define STAGE(bufi, k0s)                                                      \
  {                                                                           \
    _Pragma("unroll")                                                         \
    for (int i = 0; i < 2; ++i) {                                             \
      int rbase = wid * 16 + i * 8;                                           \
      gload_lds16(KbB + (size_t)((k0s) + rbase + srow) * DHEAD + schunk,      \
                  &Ks[bufi][rbase * 64]);                                     \
      gload_lds16(VtB + (size_t)(rbase + srow) * SEQ + (k0s) + schunk,        \
                  &Vt[bufi][rbase * 64]);                                     \
    }                                                                         \
  }

  unsigned long long mw_cur = mrow[0];
  STAGE(0, 0);
  asm volatile("s_waitcnt vmcnt(0)" ::: "memory");
  __syncthreads();

  int cur = 0;
  for (int kt = 0; kt < SEQ / 64; ++kt) {
    unsigned long long mw_next = 0;
    if (kt + 1 < SEQ / 64) {
      STAGE(cur ^ 1, (kt + 1) * 64);   // async, in flight across compute
      mw_next = mrow[kt + 1];
    }
    const short* KsC = Ks[cur];
    const short* VtC = Vt[cur];

    // QK^T: sf0 = keys 0..31, sf1 = keys 32..63 (for q = ql)
    f32x16 sf0 = {}, sf1 = {};
    __builtin_amdgcn_s_setprio(1);
#pragma unroll
    for (int ds = 0; ds < 4; ++ds) {
      s16x8 k0 = *(const s16x8*)&KsC[offK[ds]];
      s16x8 k1 = *(const s16x8*)&KsC[offK[ds] + 2048];
      sf0 = __builtin_amdgcn_mfma_f32_32x32x16_bf16(k0, qf[ds], sf0, 0, 0, 0);
      sf1 = __builtin_amdgcn_mfma_f32_32x32x16_bf16(k1, qf[ds], sf1, 0, 0, 0);
    }
    __builtin_amdgcn_s_setprio(0);

    // mask: key = kb*32 + (r&3)+8*(r>>2)+4*hi
    unsigned h0 = ((unsigned)mw_cur) >> (hi << 2);
    unsigned h1 = ((unsigned)(mw_cur >> 32)) >> (hi << 2);
#pragma unroll
    for (int r = 0; r < 16; ++r) {
      const int c = (r & 3) + 8 * (r >> 2);
      if ((h0 >> c) & 1u) sf0[r] = -1e30f;
      if ((h1 >> c) & 1u) sf1[r] = -1e30f;
    }

    // row max: 31 in-lane + 1 cross-half shfl
    float tm = sf0[0];
#pragma unroll
    for (int r = 1; r < 16; ++r) tm = fmaxf(tm, sf0[r]);
#pragma unroll
    for (int r = 0; r < 16; ++r) tm = fmaxf(tm, sf1[r]);
    tm = fmaxf(tm, __shfl_xor(tm, 32, 64));

    // defer-max (T13): skip rescale while growth <= 8 (p bounded by 2^8)
    bool small = __all(tm <= m_run + 8.0f);
    if (!small) {
      float mnew = fmaxf(m_run, tm);
      float scl = __builtin_amdgcn_exp2f(m_run - mnew);
      m_run = mnew;
      l_run *= scl;
#pragma unroll
      for (int r = 0; r < 16; ++r) {
        float s_ = __shfl(scl, (r & 3) + 8 * (r >> 2) + 4 * hi, 64);
        oacc0[r] *= s_;
        oacc1[r] *= s_;
      }
    }

    // p = exp2(s - m), row sum (own half) + cross-half shfl
    float ss = 0.f;
#pragma unroll
    for (int r = 0; r < 16; ++r) {
      sf0[r] = __builtin_amdgcn_exp2f(sf0[r] - m_run);
      sf1[r] = __builtin_amdgcn_exp2f(sf1[r] - m_run);
      ss += sf0[r] + sf1[r];
    }
    l_run += ss + __shfl_xor(ss, 32, 64);

    // PV: O[q][d] += P·V.  P stays in native slots: pa.v[e] = sf[base+e]
    // (key kappa(hi,e) = m*16 + (e&3)+8*(e>>2)+4*hi); V loaded with the SAME
    // key order via two b64 reads -> permutation cancels in the MFMA.
    __builtin_amdgcn_s_setprio(1);
#pragma unroll
    for (int m = 0; m < 4; ++m) {
      const int base = (m & 1) * 8;
      s16x8 pa;
#pragma unroll
      for (int e = 0; e < 8; ++e)
        pa[e] = f2bf(m < 2 ? sf0[base + e] : sf1[base + e]);
      union { s16x4 q[2]; s16x8 v; } v0, v1;
      v0.q[0] = *(const s16x4*)&VtC[offVa[m]];
      v0.q[1] = *(const s16x4*)&VtC[offVb[m]];
      v1.q[0] = *(const s16x4*)&VtC[offVa[m] + 2048];
      v1.q[1] = *(const s16x4*)&VtC[offVb[m] + 2048];
      oacc0 = __builtin_amdgcn_mfma_f32_32x32x16_bf16(pa, v0.v, oacc0, 0, 0, 0);
      oacc1 = __builtin_amdgcn_mfma_f32_32x32x16_bf16(pa, v1.v, oacc1, 0, 0, 0);
    }
    __builtin_amdgcn_s_setprio(0);

    asm volatile("s_waitcnt vmcnt(0)" ::: "memory");  // next tile landed
    __syncthreads();                                  // all waves done w/ cur
    cur ^= 1;
    mw_cur = mw_next;
  }
#undef STAGE

  // epilogue: oacc[r] is q' = q0 + wid*32 + crow(r,hi), d = ql (+32)
#pragma unroll
  for (int r = 0; r < 16; ++r) {
    int c = (r & 3) + 8 * (r >> 2) + 4 * hi;
    float linv = 1.0f / __shfl(l_run, c, 64);
    int q_ = q0 + wid * 32 + c;
    size_t base = ((size_t)b * SEQ + q_) * DMODEL + h * DHEAD + ql;
    Ctx[base] = f2bf(oacc0[r] * linv);
    Ctx[base + 32] = f2bf(oacc1[r] * linv);
  }
}

// ---------------------------------------------------------------------------
// Output projection: ctx bf16 @ Wo + bo -> fp32 out.  Pure glLDS,
// double-buffered, 1 barrier/K-step, XCD-swizzled (256 = 8 x 32).
// ---------------------------------------------------------------------------
__global__ __launch_bounds__(256) void proj_out_kernel(
    const short* __restrict__ Ctx, const short* __restrict__ Wot,
    const float* __restrict__ bo, float* __restrict__ Out) {
  __shared__ short As[2][128 * 32];
  __shared__ short Bs[2][128 * 32];
  int wg = blockIdx.x;
  int orig = (wg & 7) * 32 + (wg >> 3);    // bijective: 256 = 8 x 32
  int mx = orig >> 3, ny = orig & 7;
  int m0 = mx * 128, n0 = ny * 128;
  int t = threadIdx.x, wid = t >> 6, lane = t & 63;
  int lr = lane & 15, lg = lane >> 4;
  int wr = wid >> 1, wc = wid & 1;
  f32x4 acc[4][4] = {};

  const int gr0 = t >> 2, gc0 = (t & 3) << 3;
  const short* Actx0 = Ctx + (size_t)(m0 + gr0) * DMODEL + gc0;
  const short* Actx1 = Actx0 + (size_t)64 * DMODEL;
  const short* Bwo0 = Wot + (size_t)(n0 + gr0) * DMODEL + gc0;
  const short* Bwo1 = Bwo0 + (size_t)64 * DMODEL;
  const int lofs0 = (t & ~63) << 3, lofs1 = lofs0 + 256 * 8;

#define STAGE_PO(bufi, k0s) {                                                 \
    gload_lds16(Actx0 + (k0s), &As[bufi][0] + lofs0);                         \
    gload_lds16(Actx1 + (k0s), &As[bufi][0] + lofs1);                         \
    gload_lds16(Bwo0 + (k0s), &Bs[bufi][0] + lofs0);                          \
    gload_lds16(Bwo1 + (k0s), &Bs[bufi][0] + lofs1); }

  STAGE_PO(0, 0);
  __syncthreads();   // implicit vmcnt(0) drain

  int cur = 0;
  for (int kt = 0; kt < DMODEL / 32; ++kt) {
    if (kt + 1 < DMODEL / 32) STAGE_PO(cur ^ 1, (kt + 1) * 32);
    s16x8 afr[4], bfr[4];
#pragma unroll
    for (int mi = 0; mi < 4; ++mi)
      afr[mi] = *(const s16x8*)(&As[cur][0] + (wr * 64 + mi * 16 + lr) * 32 + lg * 8);
#pragma unroll
    for (int ni = 0; ni < 4; ++ni)
      bfr[ni] = *(const s16x8*)(&Bs[cur][0] + (wc * 64 + ni * 16 + lr) * 32 + lg * 8);
    __builtin_amdgcn_s_setprio(1);
#pragma unroll
    for (int mi = 0; mi < 4; ++mi)
#pragma unroll
      for (int ni = 0; ni < 4; ++ni)
        acc[mi][ni] = __builtin_amdgcn_mfma_f32_16x16x32_bf16(
            afr[mi], bfr[ni], acc[mi][ni], 0, 0, 0);
    __builtin_amdgcn_s_setprio(0);
    __syncthreads();   // drains vmcnt: next tile landed; reads of cur done
    cur ^= 1;
  }
#undef STAGE_PO

#pragma unroll
  for (int mi = 0; mi < 4; ++mi)
#pragma unroll
    for (int ni = 0; ni < 4; ++ni) {
      int n = n0 + wc * 64 + ni * 16 + lr;
      float bv_ = bo[n];
#pragma unroll
      for (int r = 0; r < 4; ++r) {
        int m = m0 + wr * 64 + mi * 16 + lg * 4 + r;
        Out[(size_t)m * DMODEL + n] = acc[mi][ni][r] + bv_;
      }
    }
}

// ---------------------------------------------------------------------------
extern "C" void kernel_launch(void* const* d_in, const int* in_sizes, int n_in,
                              void* d_out, int out_size, void* d_ws, size_t ws_size,
                              hipStream_t stream) {
  const float* key_in   = (const float*)d_in[0];
  const float* value_in = (const float*)d_in[1];
  const float* query_in = (const float*)d_in[2];
  const int*   mask     = (const int*)d_in[3];
  const float* Wq = (const float*)d_in[4];
  const float* bq = (const float*)d_in[5];
  const float* Wk = (const float*)d_in[6];
  const float* bk = (const float*)d_in[7];
  const float* Wv = (const float*)d_in[8];
  const float* bv = (const float*)d_in[9];
  const float* Wo = (const float*)d_in[10];
  const float* bo = (const float*)d_in[11];
  float* out = (float*)d_out;

  short* ws = (short*)d_ws;
  const size_t WSZ   = (size_t)DMODEL * DMODEL;              // 1M elems
  const size_t QKVSZ = (size_t)BATCH * NHEAD * SEQ * DHEAD;  // 4M elems
  short* Wt  = ws;                         // [0, 4M)   4 weights bf16
  short* QKV = ws + 4 * WSZ;               // Q [4M,8M) K [8M,12M) V^T [12M,16M)
  short* Qb  = QKV;
  short* Kb  = QKV + QKVSZ;
  short* VbT = QKV + 2 * QKVSZ;            // [bh][d][s]  (pre-transposed)
  short* Xb  = ws + 4 * WSZ + 3 * QKVSZ;   // [16M, 28M)  bf16 activations
  short* Ctx = Xb;                         // overlays Xb[query] (dead by attn)
  unsigned long long* Mp = (unsigned long long*)ws;   // overlays Wt[0] (dead)

  wtrans_kernel<<<dim3(16, 16, 4), 256, 0, stream>>>(Wq, Wk, Wv, Wo, Wt);
  xcast_kernel<<<dim3(2048, 3), 256, 0, stream>>>(query_in, key_in, value_in, Xb);
  proj_qkv_kernel<<<dim3(768), 256, 0, stream>>>(Xb, Wt, bq, bk, bv, QKV);
  mpack_kernel<<<dim3(1024), 256, 0, stream>>>(mask, Mp);
  attn_kernel<<<dim3(512), 256, 0, stream>>>(Qb, Kb, VbT, Mp, Ctx);
  proj_out_kernel<<<dim3(256), 256, 0, stream>>>(Ctx, Wt + 3 * WSZ, bo, out);
}

// Round 10
// 168.180 us; speedup vs baseline: 1.1329x; 1.0935x over previous
//
#include <hip/hip_runtime.h>
#include <hip/hip_bf16.h>

#define BATCH  2
#define SEQ    2048
#define DMODEL 1024
#define NHEAD  16
#define DHEAD  64
#define NTOK   (BATCH * SEQ)

using f32x4  = __attribute__((ext_vector_type(4))) float;
using f32x16 = __attribute__((ext_vector_type(16))) float;
using s16x4  = __attribute__((ext_vector_type(4))) short;
using s16x8  = __attribute__((ext_vector_type(8))) short;

__device__ __forceinline__ short f2bf(float f) {
  __hip_bfloat16 h = __float2bfloat16(f);
  return *(short*)&h;
}

__device__ __forceinline__ void gload_lds16(const short* g, short* l) {
  __builtin_amdgcn_global_load_lds(
      (const __attribute__((address_space(1))) void*)g,
      (__attribute__((address_space(3))) void*)l, 16, 0, 0);
}

// ---------------------------------------------------------------------------
// prep: fused wtrans (blocks 0..1023) | xcast (1024..7167) | mpack (7168..8191)
// ---------------------------------------------------------------------------
__global__ __launch_bounds__(256) void prep_kernel(
    const float* __restrict__ Wq, const float* __restrict__ Wk,
    const float* __restrict__ Wv, const float* __restrict__ Wo,
    short* __restrict__ Wt,
    const float* __restrict__ Xq, const float* __restrict__ Xk,
    const float* __restrict__ Xv, short* __restrict__ Xb,
    const int* __restrict__ mask, unsigned long long* __restrict__ Mp) {
  __shared__ short tile[64][72];
  int bid = blockIdx.x, t = threadIdx.x;
  if (bid < 1024) {
    // ---- wtrans: W[k][n] fp32 -> Wt[n][k] bf16
    int z = bid >> 8, rem = bid & 255, x = rem & 15, y = rem >> 4;
    const float* W = z == 0 ? Wq : z == 1 ? Wk : z == 2 ? Wv : Wo;
    short* out = Wt + (size_t)z * DMODEL * DMODEL;
    int k0 = x * 64, n0 = y * 64;
#pragma unroll
    for (int i = 0; i < 4; ++i) {
      int idx = t + i * 256, row = idx >> 4, c4 = idx & 15;
      f32x4 v = *(const f32x4*)(W + (size_t)(k0 + row) * DMODEL + n0 + c4 * 4);
      s16x4 p;
      p[0] = f2bf(v[0]); p[1] = f2bf(v[1]); p[2] = f2bf(v[2]); p[3] = f2bf(v[3]);
      *(s16x4*)&tile[row][c4 * 4] = p;
    }
    __syncthreads();
#pragma unroll
    for (int i = 0; i < 2; ++i) {
      int idx = t + i * 256, nrow = idx >> 3, c8 = idx & 7;
      s16x8 p;
#pragma unroll
      for (int j = 0; j < 8; ++j) p[j] = tile[c8 * 8 + j][nrow];
      *(s16x8*)(out + (size_t)(n0 + nrow) * DMODEL + k0 + c8 * 8) = p;
    }
  } else if (bid < 7168) {
    // ---- xcast: fp32 -> bf16
    int r = bid - 1024;
    int sel = r >> 11, bx = r & 2047;
    const float* src = sel == 0 ? Xq : sel == 1 ? Xk : Xv;
    size_t off = ((size_t)bx * 256 + t) * 8;
    f32x4 v0 = *(const f32x4*)(src + off);
    f32x4 v1 = *(const f32x4*)(src + off + 4);
    s16x8 p;
    p[0] = f2bf(v0[0]); p[1] = f2bf(v0[1]); p[2] = f2bf(v0[2]); p[3] = f2bf(v0[3]);
    p[4] = f2bf(v1[0]); p[5] = f2bf(v1[1]); p[6] = f2bf(v1[2]); p[7] = f2bf(v1[3]);
    *(s16x8*)(Xb + (size_t)sel * NTOK * DMODEL + off) = p;
  } else {
    // ---- mpack: bit-pack mask
    int bx = bid - 7168;
    const int total_words = BATCH * SEQ * (SEQ / 64);
    int lane = t & 63;
    int wv = bx * 4 + (t >> 6);
    for (int w = wv; w < total_words; w += 4096) {
      int mv = mask[(size_t)w * 64 + lane];
      unsigned long long bits = __ballot(mv != 0);
      if (lane == 0) Mp[w] = bits;
    }
  }
}

// ---------------------------------------------------------------------------
// QKV projection: Xb bf16 @ Wt^T + b -> bf16.  3-buffer counted-vmcnt
// pipeline (T4), 1 raw barrier/K-step.  XCD-swizzled (768 = 8 x 96).
// Q,K -> [bh][s][d] (Q pre-scaled); V -> [bh][d][s].  grid 768, block 256.
// ---------------------------------------------------------------------------
__global__ __launch_bounds__(256) void proj_qkv_kernel(
    const short* __restrict__ Xb, const short* __restrict__ Wt,
    const float* __restrict__ bq, const float* __restrict__ bk,
    const float* __restrict__ bv, short* __restrict__ QKV) {
  __shared__ short As[3][128 * 32];
  __shared__ short Bs[3][128 * 32];
  int wg = blockIdx.x;
  int orig = (wg & 7) * 96 + (wg >> 3);
  int sel = orig >> 8;
  int rem = orig & 255;
  int mx = rem >> 3, ny = rem & 7;

  const short* X    = Xb + (size_t)sel * NTOK * DMODEL;
  const float* bias = sel == 0 ? bq : sel == 1 ? bk : bv;
  const short* Wsel = Wt + (size_t)sel * DMODEL * DMODEL;
  short* Obuf = QKV + (size_t)sel * ((size_t)BATCH * NHEAD * SEQ * DHEAD);
  const float scale = sel == 0 ? 0.18033688011111793f : 1.0f;  // (1/8)*log2e

  int m0 = mx * 128, n0 = ny * 128;
  int t = threadIdx.x, wid = t >> 6, lane = t & 63;
  int lr = lane & 15, lg = lane >> 4;
  int wr = wid >> 1, wc = wid & 1;
  f32x4 acc[4][4] = {};

  const int gr0 = t >> 2, gc0 = (t & 3) << 3;
  const short* Ax0 = X + (size_t)(m0 + gr0) * DMODEL + gc0;
  const short* Ax1 = Ax0 + (size_t)64 * DMODEL;
  const short* Bw0 = Wsel + (size_t)(n0 + gr0) * DMODEL + gc0;
  const short* Bw1 = Bw0 + (size_t)64 * DMODEL;
  const int lofs0 = (t & ~63) << 3, lofs1 = lofs0 + 256 * 8;

#define STAGEQ(bufi, k0s) {                                                   \
    gload_lds16(Ax0 + (k0s), &As[bufi][0] + lofs0);                           \
    gload_lds16(Ax1 + (k0s), &As[bufi][0] + lofs1);                           \
    gload_lds16(Bw0 + (k0s), &Bs[bufi][0] + lofs0);                           \
    gload_lds16(Bw1 + (k0s), &Bs[bufi][0] + lofs1); }

  STAGEQ(0, 0);
  STAGEQ(1, 32);

  int cb = 0;
  for (int kt = 0; kt < 32; ++kt) {
    if (kt + 1 < 32) { asm volatile("s_waitcnt vmcnt(4)" ::: "memory"); }
    else             { asm volatile("s_waitcnt vmcnt(0)" ::: "memory"); }
    __builtin_amdgcn_sched_barrier(0);
    __builtin_amdgcn_s_barrier();
    __builtin_amdgcn_sched_barrier(0);
    int st = cb + 2; if (st > 2) st -= 3;
    if (kt + 2 < 32) STAGEQ(st, (kt + 2) * 32);

    s16x8 afr[4], bfr[4];
#pragma unroll
    for (int mi = 0; mi < 4; ++mi)
      afr[mi] = *(const s16x8*)(&As[cb][0] + (wr * 64 + mi * 16 + lr) * 32 + lg * 8);
#pragma unroll
    for (int ni = 0; ni < 4; ++ni)
      bfr[ni] = *(const s16x8*)(&Bs[cb][0] + (wc * 64 + ni * 16 + lr) * 32 + lg * 8);
    __builtin_amdgcn_s_setprio(1);
#pragma unroll
    for (int mi = 0; mi < 4; ++mi)
#pragma unroll
      for (int ni = 0; ni < 4; ++ni)
        acc[mi][ni] = __builtin_amdgcn_mfma_f32_16x16x32_bf16(
            afr[mi], bfr[ni], acc[mi][ni], 0, 0, 0);
    __builtin_amdgcn_s_setprio(0);
    cb = (cb == 2) ? 0 : cb + 1;
  }
#undef STAGEQ

  if (sel == 2) {
    int bq_ = m0 >> 11;
    int s0 = (m0 & (SEQ - 1)) + wr * 64 + lg * 4;
#pragma unroll
    for (int mi = 0; mi < 4; ++mi)
#pragma unroll
      for (int ni = 0; ni < 4; ++ni) {
        int n = n0 + wc * 64 + ni * 16 + lr;
        float bv_ = bias[n];
        int h = n >> 6, d = n & 63;
        s16x4 pk;
#pragma unroll
        for (int r = 0; r < 4; ++r) pk[r] = f2bf(acc[mi][ni][r] + bv_);
        *(s16x4*)&Obuf[((size_t)(bq_ * NHEAD + h) * DHEAD + d) * SEQ
                       + s0 + mi * 16] = pk;
      }
  } else {
#pragma unroll
    for (int mi = 0; mi < 4; ++mi)
#pragma unroll
      for (int ni = 0; ni < 4; ++ni) {
        int n = n0 + wc * 64 + ni * 16 + lr;
        float bv_ = bias[n];
        int h = n >> 6, d = n & 63;
#pragma unroll
        for (int r = 0; r < 4; ++r) {
          int m = m0 + wr * 64 + mi * 16 + lg * 4 + r;
          int b = m >> 11, s = m & (SEQ - 1);
          float val = (acc[mi][ni][r] + bv_) * scale;
          Obuf[((size_t)(b * NHEAD + h) * SEQ + s) * DHEAD + d] = f2bf(val);
        }
      }
  }
}

// ---------------------------------------------------------------------------
// Flash attention, 32x32 swapped QK^T, in-register softmax (round-9 verified
// fragment math).  3-buffer counted-vmcnt pipeline; per-half running l (merge
// at epilogue); cross-half max shfl only on rare rescale.  grid 512, block 256.
// ---------------------------------------------------------------------------
__global__ __launch_bounds__(256) void attn_kernel(
    const short* __restrict__ Qb, const short* __restrict__ Kb,
    const short* __restrict__ VbT, const unsigned long long* __restrict__ Mp,
    short* __restrict__ Ctx) {
  __shared__ short Ks[3][64 * 64];    // [key][d], 16B-chunk c ^= key&7
  __shared__ short Vt[3][64 * 64];    // [d][key], chunk c ^= d&7
  int wg = blockIdx.x;
  int orig = (wg & 7) * 64 + (wg >> 3);    // bijective: 512 = 8 x 64
  int bh = orig >> 4, qt = orig & 15;
  int b = bh >> 4, h = bh & 15;
  int q0 = qt * 128;
  int t = threadIdx.x, wid = t >> 6, lane = t & 63;
  int ql = lane & 31, hi = lane >> 5;
  int qrow = q0 + wid * 32 + ql;

  const short* Qp = Qb + ((size_t)bh * SEQ + qrow) * DHEAD + hi * 8;
  s16x8 qf[4];
#pragma unroll
  for (int ds = 0; ds < 4; ++ds) qf[ds] = *(const s16x8*)(Qp + ds * 16);

  const short* KbB = Kb + (size_t)bh * SEQ * DHEAD;    // [key][d]
  const short* VtB = VbT + (size_t)bh * DHEAD * SEQ;   // [d][key]

  const int srow = lane >> 3;
  const int schunk = ((lane & 7) ^ srow) * 8;

  int offK[4];
#pragma unroll
  for (int j = 0; j < 4; ++j)
    offK[j] = ql * 64 + (((j * 2 + hi) ^ (ql & 7)) << 3);
  int offVa[4], offVb[4];
#pragma unroll
  for (int m = 0; m < 4; ++m) {
    offVa[m] = ql * 64 + (((m * 2)     ^ (ql & 7)) << 3) + 4 * hi;
    offVb[m] = ql * 64 + (((m * 2 + 1) ^ (ql & 7)) << 3) + 4 * hi;
  }

  float m_run = -1e30f, l_run = 0.f;   // l_run = OWN-HALF partial sum
  f32x16 oacc0 = {}, oacc1 = {};

  const unsigned long long* mrow = Mp + ((size_t)b * SEQ + qrow) * (SEQ / 64);

#define STAGE(bufi, k0s)                                                      \
  {                                                                           \
    _Pragma("unroll")                                                         \
    for (int i = 0; i < 2; ++i) {                                             \
      int rbase = wid * 16 + i * 8;                                           \
      gload_lds16(KbB + (size_t)((k0s) + rbase + srow) * DHEAD + schunk,      \
                  &Ks[bufi][rbase * 64]);                                     \
      gload_lds16(VtB + (size_t)(rbase + srow) * SEQ + (k0s) + schunk,        \
                  &Vt[bufi][rbase * 64]);                                     \
    }                                                                         \
  }

  unsigned long long mwq0 = mrow[0], mwq1 = mrow[1];
  STAGE(0, 0);
  STAGE(1, 64);

  int cb = 0;
  for (int kt = 0; kt < 32; ++kt) {
    if (kt + 1 < 32) { asm volatile("s_waitcnt vmcnt(4)" ::: "memory"); }
    else             { asm volatile("s_waitcnt vmcnt(0)" ::: "memory"); }
    __builtin_amdgcn_sched_barrier(0);
    __builtin_amdgcn_s_barrier();
    __builtin_amdgcn_sched_barrier(0);
    int st = cb + 2; if (st > 2) st -= 3;
    if (kt + 2 < 32) STAGE(st, (kt + 2) * 64);
    unsigned long long mw_cur = mwq0;
    mwq0 = mwq1;
    if (kt + 2 < 32) mwq1 = mrow[kt + 2];

    const short* KsC = Ks[cb];
    const short* VtC = Vt[cb];

    // QK^T
    f32x16 sf0 = {}, sf1 = {};
    __builtin_amdgcn_s_setprio(1);
#pragma unroll
    for (int ds = 0; ds < 4; ++ds) {
      s16x8 k0 = *(const s16x8*)&KsC[offK[ds]];
      s16x8 k1 = *(const s16x8*)&KsC[offK[ds] + 2048];
      sf0 = __builtin_amdgcn_mfma_f32_32x32x16_bf16(k0, qf[ds], sf0, 0, 0, 0);
      sf1 = __builtin_amdgcn_mfma_f32_32x32x16_bf16(k1, qf[ds], sf1, 0, 0, 0);
    }
    __builtin_amdgcn_s_setprio(0);

    // mask: key = kb*32 + (r&3)+8*(r>>2)+4*hi
    unsigned h0 = ((unsigned)mw_cur) >> (hi << 2);
    unsigned h1 = ((unsigned)(mw_cur >> 32)) >> (hi << 2);
#pragma unroll
    for (int r = 0; r < 16; ++r) {
      const int c = (r & 3) + 8 * (r >> 2);
      if ((h0 >> c) & 1u) sf0[r] = -1e30f;
      if ((h1 >> c) & 1u) sf1[r] = -1e30f;
    }

    // per-half max (lanes' halves cover disjoint keys): no cross-lane op
    float tm = sf0[0];
#pragma unroll
    for (int r = 1; r < 16; ++r) tm = fmaxf(tm, sf0[r]);
#pragma unroll
    for (int r = 0; r < 16; ++r) tm = fmaxf(tm, sf1[r]);

    // defer-max: __all spans both halves, so either half can trigger
    bool small = __all(tm <= m_run + 8.0f);
    if (!small) {
      float tmx = fmaxf(tm, __shfl_xor(tm, 32, 64));   // rare path only
      float mnew = fmaxf(m_run, tmx);
      float scl = __builtin_amdgcn_exp2f(m_run - mnew);
      m_run = mnew;
      l_run *= scl;
#pragma unroll
      for (int r = 0; r < 16; ++r) {
        float s_ = __shfl(scl, (r & 3) + 8 * (r >> 2) + 4 * hi, 64);
        oacc0[r] *= s_;
        oacc1[r] *= s_;
      }
    }

    // p = exp2(s - m), own-half running sum (merge at epilogue)
    float ss = 0.f;
#pragma unroll
    for (int r = 0; r < 16; ++r) {
      sf0[r] = __builtin_amdgcn_exp2f(sf0[r] - m_run);
      sf1[r] = __builtin_amdgcn_exp2f(sf1[r] - m_run);
      ss += sf0[r] + sf1[r];
    }
    l_run += ss;

    // PV (native-slot P, matching interleaved V reads — round-9 verified)
    __builtin_amdgcn_s_setprio(1);
#pragma unroll
    for (int m = 0; m < 4; ++m) {
      const int base = (m & 1) * 8;
      s16x8 pa;
#pragma unroll
      for (int e = 0; e < 8; ++e)
        pa[e] = f2bf(m < 2 ? sf0[base + e] : sf1[base + e]);
      union { s16x4 q[2]; s16x8 v; } v0, v1;
      v0.q[0] = *(const s16x4*)&VtC[offVa[m]];
      v0.q[1] = *(const s16x4*)&VtC[offVb[m]];
      v1.q[0] = *(const s16x4*)&VtC[offVa[m] + 2048];
      v1.q[1] = *(const s16x4*)&VtC[offVb[m] + 2048];
      oacc0 = __builtin_amdgcn_mfma_f32_32x32x16_bf16(pa, v0.v, oacc0, 0, 0, 0);
      oacc1 = __builtin_amdgcn_mfma_f32_32x32x16_bf16(pa, v1.v, oacc1, 0, 0, 0);
    }
    __builtin_amdgcn_s_setprio(0);
    cb = (cb == 2) ? 0 : cb + 1;
  }
#undef STAGE

  // epilogue: merge half-sums, then divide (oacc[r]: q'=crow(r,hi), d=ql)
  float l_tot = l_run + __shfl_xor(l_run, 32, 64);
#pragma unroll
  for (int r = 0; r < 16; ++r) {
    int c = (r & 3) + 8 * (r >> 2) + 4 * hi;
    float linv = 1.0f / __shfl(l_tot, c, 64);
    int q_ = q0 + wid * 32 + c;
    size_t base = ((size_t)b * SEQ + q_) * DMODEL + h * DHEAD + ql;
    Ctx[base] = f2bf(oacc0[r] * linv);
    Ctx[base + 32] = f2bf(oacc1[r] * linv);
  }
}

// ---------------------------------------------------------------------------
// Output projection: ctx bf16 @ Wo + bo -> fp32 out.  3-buffer counted-vmcnt
// pipeline, XCD-swizzled (256 = 8 x 32).  grid 256, block 256.
// ---------------------------------------------------------------------------
__global__ __launch_bounds__(256) void proj_out_kernel(
    const short* __restrict__ Ctx, const short* __restrict__ Wot,
    const float* __restrict__ bo, float* __restrict__ Out) {
  __shared__ short As[3][128 * 32];
  __shared__ short Bs[3][128 * 32];
  int wg = blockIdx.x;
  int orig = (wg & 7) * 32 + (wg >> 3);
  int mx = orig >> 3, ny = orig & 7;
  int m0 = mx * 128, n0 = ny * 128;
  int t = threadIdx.x, wid = t >> 6, lane = t & 63;
  int lr = lane & 15, lg = lane >> 4;
  int wr = wid >> 1, wc = wid & 1;
  f32x4 acc[4][4] = {};

  const int gr0 = t >> 2, gc0 = (t & 3) << 3;
  const short* Actx0 = Ctx + (size_t)(m0 + gr0) * DMODEL + gc0;
  const short* Actx1 = Actx0 + (size_t)64 * DMODEL;
  const short* Bwo0 = Wot + (size_t)(n0 + gr0) * DMODEL + gc0;
  const short* Bwo1 = Bwo0 + (size_t)64 * DMODEL;
  const int lofs0 = (t & ~63) << 3, lofs1 = lofs0 + 256 * 8;

#define STAGE_PO(bufi, k0s) {                                                 \
    gload_lds16(Actx0 + (k0s), &As[bufi][0] + lofs0);                         \
    gload_lds16(Actx1 + (k0s), &As[bufi][0] + lofs1);                         \
    gload_lds16(Bwo0 + (k0s), &Bs[bufi][0] + lofs0);                          \
    gload_lds16(Bwo1 + (k0s), &Bs[bufi][0] + lofs1); }

  STAGE_PO(0, 0);
  STAGE_PO(1, 32);

  int cb = 0;
  for (int kt = 0; kt < 32; ++kt) {
    if (kt + 1 < 32) { asm volatile("s_waitcnt vmcnt(4)" ::: "memory"); }
    else             { asm volatile("s_waitcnt vmcnt(0)" ::: "memory"); }
    __builtin_amdgcn_sched_barrier(0);
    __builtin_amdgcn_s_barrier();
    __builtin_amdgcn_sched_barrier(0);
    int st = cb + 2; if (st > 2) st -= 3;
    if (kt + 2 < 32) STAGE_PO(st, (kt + 2) * 32);

    s16x8 afr[4], bfr[4];
#pragma unroll
    for (int mi = 0; mi < 4; ++mi)
      afr[mi] = *(const s16x8*)(&As[cb][0] + (wr * 64 + mi * 16 + lr) * 32 + lg * 8);
#pragma unroll
    for (int ni = 0; ni < 4; ++ni)
      bfr[ni] = *(const s16x8*)(&Bs[cb][0] + (wc * 64 + ni * 16 + lr) * 32 + lg * 8);
    __builtin_amdgcn_s_setprio(1);
#pragma unroll
    for (int mi = 0; mi < 4; ++mi)
#pragma unroll
      for (int ni = 0; ni < 4; ++ni)
        acc[mi][ni] = __builtin_amdgcn_mfma_f32_16x16x32_bf16(
            afr[mi], bfr[ni], acc[mi][ni], 0, 0, 0);
    __builtin_amdgcn_s_setprio(0);
    cb = (cb == 2) ? 0 : cb + 1;
  }
#undef STAGE_PO

#pragma unroll
  for (int mi = 0; mi < 4; ++mi)
#pragma unroll
    for (int ni = 0; ni < 4; ++ni) {
      int n = n0 + wc * 64 + ni * 16 + lr;
      float bv_ = bo[n];
#pragma unroll
      for (int r = 0; r < 4; ++r) {
        int m = m0 + wr * 64 + mi * 16 + lg * 4 + r;
        Out[(size_t)m * DMODEL + n] = acc[mi][ni][r] + bv_;
      }
    }
}

// ---------------------------------------------------------------------------
extern "C" void kernel_launch(void* const* d_in, const int* in_sizes, int n_in,
                              void* d_out, int out_size, void* d_ws, size_t ws_size,
                              hipStream_t stream) {
  const float* key_in   = (const float*)d_in[0];
  const float* value_in = (const float*)d_in[1];
  const float* query_in = (const float*)d_in[2];
  const int*   mask     = (const int*)d_in[3];
  const float* Wq = (const float*)d_in[4];
  const float* bq = (const float*)d_in[5];
  const float* Wk = (const float*)d_in[6];
  const float* bk = (const float*)d_in[7];
  const float* Wv = (const float*)d_in[8];
  const float* bv = (const float*)d_in[9];
  const float* Wo = (const float*)d_in[10];
  const float* bo = (const float*)d_in[11];
  float* out = (float*)d_out;

  short* ws = (short*)d_ws;
  const size_t WSZ   = (size_t)DMODEL * DMODEL;              // 1M elems
  const size_t QKVSZ = (size_t)BATCH * NHEAD * SEQ * DHEAD;  // 4M elems
  short* Wt  = ws;                         // [0, 4M)   4 weights bf16
  short* QKV = ws + 4 * WSZ;               // Q [4M,8M) K [8M,12M) V^T [12M,16M)
  short* Qb  = QKV;
  short* Kb  = QKV + QKVSZ;
  short* VbT = QKV + 2 * QKVSZ;            // [bh][d][s]
  short* Xb  = ws + 4 * WSZ + 3 * QKVSZ;   // [16M, 28M)  bf16 activations
  short* Ctx = Xb;                         // overlays Xb[query] (dead by attn)
  // Mp lives in d_out (1MB << 16MB): written by prep, consumed by attn,
  // fully overwritten by proj_out afterwards (stream-serial, capture-safe).
  unsigned long long* Mp = (unsigned long long*)d_out;

  prep_kernel<<<dim3(8192), 256, 0, stream>>>(
      Wq, Wk, Wv, Wo, Wt, query_in, key_in, value_in, Xb, mask, Mp);
  proj_qkv_kernel<<<dim3(768), 256, 0, stream>>>(Xb, Wt, bq, bk, bv, QKV);
  attn_kernel<<<dim3(512), 256, 0, stream>>>(Qb, Kb, VbT, Mp, Ctx);
  proj_out_kernel<<<dim3(256), 256, 0, stream>>>(Ctx, Wt + 3 * WSZ, bo, out);
}

// Round 11
// 163.106 us; speedup vs baseline: 1.1682x; 1.0311x over previous
//
#include <hip/hip_runtime.h>
#include <hip/hip_bf16.h>

#define BATCH  2
#define SEQ    2048
#define DMODEL 1024
#define NHEAD  16
#define DHEAD  64
#define NTOK   (BATCH * SEQ)

using f32x4  = __attribute__((ext_vector_type(4))) float;
using f32x16 = __attribute__((ext_vector_type(16))) float;
using s16x4  = __attribute__((ext_vector_type(4))) short;
using s16x8  = __attribute__((ext_vector_type(8))) short;

__device__ __forceinline__ short f2bf(float f) {
  __hip_bfloat16 h = __float2bfloat16(f);
  return *(short*)&h;
}

__device__ __forceinline__ void gload_lds16(const short* g, short* l) {
  __builtin_amdgcn_global_load_lds(
      (const __attribute__((address_space(1))) void*)g,
      (__attribute__((address_space(3))) void*)l, 16, 0, 0);
}

// ---------------------------------------------------------------------------
// prep: fused wtrans (blocks 0..1023) | xcast (1024..7167) | mpack (7168..8191)
// ---------------------------------------------------------------------------
__global__ __launch_bounds__(256) void prep_kernel(
    const float* __restrict__ Wq, const float* __restrict__ Wk,
    const float* __restrict__ Wv, const float* __restrict__ Wo,
    short* __restrict__ Wt,
    const float* __restrict__ Xq, const float* __restrict__ Xk,
    const float* __restrict__ Xv, short* __restrict__ Xb,
    const int* __restrict__ mask, unsigned long long* __restrict__ Mp) {
  __shared__ short tile[64][72];
  int bid = blockIdx.x, t = threadIdx.x;
  if (bid < 1024) {
    int z = bid >> 8, rem = bid & 255, x = rem & 15, y = rem >> 4;
    const float* W = z == 0 ? Wq : z == 1 ? Wk : z == 2 ? Wv : Wo;
    short* out = Wt + (size_t)z * DMODEL * DMODEL;
    int k0 = x * 64, n0 = y * 64;
#pragma unroll
    for (int i = 0; i < 4; ++i) {
      int idx = t + i * 256, row = idx >> 4, c4 = idx & 15;
      f32x4 v = *(const f32x4*)(W + (size_t)(k0 + row) * DMODEL + n0 + c4 * 4);
      s16x4 p;
      p[0] = f2bf(v[0]); p[1] = f2bf(v[1]); p[2] = f2bf(v[2]); p[3] = f2bf(v[3]);
      *(s16x4*)&tile[row][c4 * 4] = p;
    }
    __syncthreads();
#pragma unroll
    for (int i = 0; i < 2; ++i) {
      int idx = t + i * 256, nrow = idx >> 3, c8 = idx & 7;
      s16x8 p;
#pragma unroll
      for (int j = 0; j < 8; ++j) p[j] = tile[c8 * 8 + j][nrow];
      *(s16x8*)(out + (size_t)(n0 + nrow) * DMODEL + k0 + c8 * 8) = p;
    }
  } else if (bid < 7168) {
    int r = bid - 1024;
    int sel = r >> 11, bx = r & 2047;
    const float* src = sel == 0 ? Xq : sel == 1 ? Xk : Xv;
    size_t off = ((size_t)bx * 256 + t) * 8;
    f32x4 v0 = *(const f32x4*)(src + off);
    f32x4 v1 = *(const f32x4*)(src + off + 4);
    s16x8 p;
    p[0] = f2bf(v0[0]); p[1] = f2bf(v0[1]); p[2] = f2bf(v0[2]); p[3] = f2bf(v0[3]);
    p[4] = f2bf(v1[0]); p[5] = f2bf(v1[1]); p[6] = f2bf(v1[2]); p[7] = f2bf(v1[3]);
    *(s16x8*)(Xb + (size_t)sel * NTOK * DMODEL + off) = p;
  } else {
    int bx = bid - 7168;
    const int total_words = BATCH * SEQ * (SEQ / 64);
    int lane = t & 63;
    int wv = bx * 4 + (t >> 6);
    for (int w = wv; w < total_words; w += 4096) {
      int mv = mask[(size_t)w * 64 + lane];
      unsigned long long bits = __ballot(mv != 0);
      if (lane == 0) Mp[w] = bits;
    }
  }
}

// ---------------------------------------------------------------------------
// QKV projection: Xb bf16 @ Wt^T + b -> bf16.  3-buffer counted-vmcnt
// pipeline, 1 raw barrier/K-step, XCD-swizzled (768 = 8 x 96).
// Q,K -> [bh][s][d] (Q pre-scaled); V -> [bh][d][s].  grid 768, block 256.
// ---------------------------------------------------------------------------
__global__ __launch_bounds__(256) void proj_qkv_kernel(
    const short* __restrict__ Xb, const short* __restrict__ Wt,
    const float* __restrict__ bq, const float* __restrict__ bk,
    const float* __restrict__ bv, short* __restrict__ QKV) {
  __shared__ short As[3][128 * 32];
  __shared__ short Bs[3][128 * 32];
  int wg = blockIdx.x;
  int orig = (wg & 7) * 96 + (wg >> 3);
  int sel = orig >> 8;
  int rem = orig & 255;
  int mx = rem >> 3, ny = rem & 7;

  const short* X    = Xb + (size_t)sel * NTOK * DMODEL;
  const float* bias = sel == 0 ? bq : sel == 1 ? bk : bv;
  const short* Wsel = Wt + (size_t)sel * DMODEL * DMODEL;
  short* Obuf = QKV + (size_t)sel * ((size_t)BATCH * NHEAD * SEQ * DHEAD);
  const float scale = sel == 0 ? 0.18033688011111793f : 1.0f;  // (1/8)*log2e

  int m0 = mx * 128, n0 = ny * 128;
  int t = threadIdx.x, wid = t >> 6, lane = t & 63;
  int lr = lane & 15, lg = lane >> 4;
  int wr = wid >> 1, wc = wid & 1;
  f32x4 acc[4][4] = {};

  const int gr0 = t >> 2, gc0 = (t & 3) << 3;
  const short* Ax0 = X + (size_t)(m0 + gr0) * DMODEL + gc0;
  const short* Ax1 = Ax0 + (size_t)64 * DMODEL;
  const short* Bw0 = Wsel + (size_t)(n0 + gr0) * DMODEL + gc0;
  const short* Bw1 = Bw0 + (size_t)64 * DMODEL;
  const int lofs0 = (t & ~63) << 3, lofs1 = lofs0 + 256 * 8;

#define STAGEQ(bufi, k0s) {                                                   \
    gload_lds16(Ax0 + (k0s), &As[bufi][0] + lofs0);                           \
    gload_lds16(Ax1 + (k0s), &As[bufi][0] + lofs1);                           \
    gload_lds16(Bw0 + (k0s), &Bs[bufi][0] + lofs0);                           \
    gload_lds16(Bw1 + (k0s), &Bs[bufi][0] + lofs1); }

  STAGEQ(0, 0);
  STAGEQ(1, 32);

  int cb = 0;
  for (int kt = 0; kt < 32; ++kt) {
    if (kt + 1 < 32) { asm volatile("s_waitcnt vmcnt(4)" ::: "memory"); }
    else             { asm volatile("s_waitcnt vmcnt(0)" ::: "memory"); }
    __builtin_amdgcn_sched_barrier(0);
    __builtin_amdgcn_s_barrier();
    __builtin_amdgcn_sched_barrier(0);
    int st = cb + 2; if (st > 2) st -= 3;
    if (kt + 2 < 32) STAGEQ(st, (kt + 2) * 32);

    s16x8 afr[4], bfr[4];
#pragma unroll
    for (int mi = 0; mi < 4; ++mi)
      afr[mi] = *(const s16x8*)(&As[cb][0] + (wr * 64 + mi * 16 + lr) * 32 + lg * 8);
#pragma unroll
    for (int ni = 0; ni < 4; ++ni)
      bfr[ni] = *(const s16x8*)(&Bs[cb][0] + (wc * 64 + ni * 16 + lr) * 32 + lg * 8);
    __builtin_amdgcn_s_setprio(1);
#pragma unroll
    for (int mi = 0; mi < 4; ++mi)
#pragma unroll
      for (int ni = 0; ni < 4; ++ni)
        acc[mi][ni] = __builtin_amdgcn_mfma_f32_16x16x32_bf16(
            afr[mi], bfr[ni], acc[mi][ni], 0, 0, 0);
    __builtin_amdgcn_s_setprio(0);
    cb = (cb == 2) ? 0 : cb + 1;
  }
#undef STAGEQ

  if (sel == 2) {
    int bq_ = m0 >> 11;
    int s0 = (m0 & (SEQ - 1)) + wr * 64 + lg * 4;
#pragma unroll
    for (int mi = 0; mi < 4; ++mi)
#pragma unroll
      for (int ni = 0; ni < 4; ++ni) {
        int n = n0 + wc * 64 + ni * 16 + lr;
        float bv_ = bias[n];
        int h = n >> 6, d = n & 63;
        s16x4 pk;
#pragma unroll
        for (int r = 0; r < 4; ++r) pk[r] = f2bf(acc[mi][ni][r] + bv_);
        *(s16x4*)&Obuf[((size_t)(bq_ * NHEAD + h) * DHEAD + d) * SEQ
                       + s0 + mi * 16] = pk;
      }
  } else {
#pragma unroll
    for (int mi = 0; mi < 4; ++mi)
#pragma unroll
      for (int ni = 0; ni < 4; ++ni) {
        int n = n0 + wc * 64 + ni * 16 + lr;
        float bv_ = bias[n];
        int h = n >> 6, d = n & 63;
#pragma unroll
        for (int r = 0; r < 4; ++r) {
          int m = m0 + wr * 64 + mi * 16 + lg * 4 + r;
          int b = m >> 11, s = m & (SEQ - 1);
          float val = (acc[mi][ni][r] + bv_) * scale;
          Obuf[((size_t)(b * NHEAD + h) * SEQ + s) * DHEAD + d] = f2bf(val);
        }
      }
  }
}

// ---------------------------------------------------------------------------
// Flash attention, 32x32 swapped QK^T, in-register softmax, SKEWED pipeline:
// iter t issues QK^T(t) then PV(t-1) (pure-reg: P packed + V pre-read last
// iter) so softmax(t) VALU overlaps the matrix pipe.  Flash algebra exact:
// PV(t-1) lands in oacc before softmax(t)'s rescale reads oacc (reg dep).
// 3-buffer counted-vmcnt staging; grid 512 (8x64 XCD swizzle), block 256.
// ---------------------------------------------------------------------------
__global__ __launch_bounds__(256) void attn_kernel(
    const short* __restrict__ Qb, const short* __restrict__ Kb,
    const short* __restrict__ VbT, const unsigned long long* __restrict__ Mp,
    short* __restrict__ Ctx) {
  __shared__ short Ks[3][64 * 64];    // [key][d], 16B-chunk c ^= key&7
  __shared__ short Vt[3][64 * 64];    // [d][key], chunk c ^= d&7
  int wg = blockIdx.x;
  int orig = (wg & 7) * 64 + (wg >> 3);    // bijective: 512 = 8 x 64
  int bh = orig >> 4, qt = orig & 15;
  int b = bh >> 4, h = bh & 15;
  int q0 = qt * 128;
  int t = threadIdx.x, wid = t >> 6, lane = t & 63;
  int ql = lane & 31, hi = lane >> 5;
  int qrow = q0 + wid * 32 + ql;

  const short* Qp = Qb + ((size_t)bh * SEQ + qrow) * DHEAD + hi * 8;
  s16x8 qf[4];
#pragma unroll
  for (int ds = 0; ds < 4; ++ds) qf[ds] = *(const s16x8*)(Qp + ds * 16);

  const short* KbB = Kb + (size_t)bh * SEQ * DHEAD;    // [key][d]
  const short* VtB = VbT + (size_t)bh * DHEAD * SEQ;   // [d][key]

  const int srow = lane >> 3;
  const int schunk = ((lane & 7) ^ srow) * 8;

  int offK[4];
#pragma unroll
  for (int j = 0; j < 4; ++j)
    offK[j] = ql * 64 + (((j * 2 + hi) ^ (ql & 7)) << 3);
  int offVa[4], offVb[4];
#pragma unroll
  for (int m = 0; m < 4; ++m) {
    offVa[m] = ql * 64 + (((m * 2)     ^ (ql & 7)) << 3) + 4 * hi;
    offVb[m] = ql * 64 + (((m * 2 + 1) ^ (ql & 7)) << 3) + 4 * hi;
  }

  float m_run = -1e30f, l_run = 0.f;   // l_run = OWN-HALF partial sum
  f32x16 oacc0 = {}, oacc1 = {};
  s16x8 pPack[4];                      // P(t-1) bf16 fragments (native slots)
  s16x8 vA[4], vB[4];                  // V(t-1) fragments, d=ql / d=ql+32

  const unsigned long long* mrow = Mp + ((size_t)b * SEQ + qrow) * (SEQ / 64);

#define STAGE(bufi, k0s)                                                      \
  {                                                                           \
    _Pragma("unroll")                                                         \
    for (int i = 0; i < 2; ++i) {                                             \
      int rbase = wid * 16 + i * 8;                                           \
      gload_lds16(KbB + (size_t)((k0s) + rbase + srow) * DHEAD + schunk,      \
                  &Ks[bufi][rbase * 64]);                                     \
      gload_lds16(VtB + (size_t)(rbase + srow) * SEQ + (k0s) + schunk,        \
                  &Vt[bufi][rbase * 64]);                                     \
    }                                                                         \
  }

  unsigned long long mwq0 = mrow[0], mwq1 = mrow[1];
  STAGE(0, 0);
  STAGE(1, 64);

  int cb = 0;
  for (int kt = 0; kt < 32; ++kt) {
    if (kt + 1 < 32) { asm volatile("s_waitcnt vmcnt(4)" ::: "memory"); }
    else             { asm volatile("s_waitcnt vmcnt(0)" ::: "memory"); }
    __builtin_amdgcn_sched_barrier(0);
    __builtin_amdgcn_s_barrier();
    __builtin_amdgcn_sched_barrier(0);
    int st = cb + 2; if (st > 2) st -= 3;
    if (kt + 2 < 32) STAGE(st, (kt + 2) * 64);
    unsigned long long mw_cur = mwq0;
    mwq0 = mwq1;
    if (kt + 2 < 32) mwq1 = mrow[kt + 2];

    const short* KsC = Ks[cb];
    const short* VtC = Vt[cb];

    // QK^T(t): issue 16 MFMAs
    f32x16 sf0 = {}, sf1 = {};
    __builtin_amdgcn_s_setprio(1);
#pragma unroll
    for (int ds = 0; ds < 4; ++ds) {
      s16x8 k0 = *(const s16x8*)&KsC[offK[ds]];
      s16x8 k1 = *(const s16x8*)&KsC[offK[ds] + 2048];
      sf0 = __builtin_amdgcn_mfma_f32_32x32x16_bf16(k0, qf[ds], sf0, 0, 0, 0);
      sf1 = __builtin_amdgcn_mfma_f32_32x32x16_bf16(k1, qf[ds], sf1, 0, 0, 0);
    }
    // PV(t-1): pure-reg MFMAs queue behind QK^T; execute under softmax VALU
    if (kt > 0) {
#pragma unroll
      for (int m = 0; m < 4; ++m) {
        oacc0 = __builtin_amdgcn_mfma_f32_32x32x16_bf16(pPack[m], vA[m], oacc0, 0, 0, 0);
        oacc1 = __builtin_amdgcn_mfma_f32_32x32x16_bf16(pPack[m], vB[m], oacc1, 0, 0, 0);
      }
    }
    __builtin_amdgcn_s_setprio(0);

    // V fragments of THIS tile (used by PV at iter t+1) — issue reads early
#pragma unroll
    for (int m = 0; m < 4; ++m) {
      union { s16x4 q[2]; s16x8 v; } v0, v1;
      v0.q[0] = *(const s16x4*)&VtC[offVa[m]];
      v0.q[1] = *(const s16x4*)&VtC[offVb[m]];
      v1.q[0] = *(const s16x4*)&VtC[offVa[m] + 2048];
      v1.q[1] = *(const s16x4*)&VtC[offVb[m] + 2048];
      vA[m] = v0.v;
      vB[m] = v1.v;
    }

    // softmax(t) — overlaps the queued MFMAs
    unsigned h0 = ((unsigned)mw_cur) >> (hi << 2);
    unsigned h1 = ((unsigned)(mw_cur >> 32)) >> (hi << 2);
#pragma unroll
    for (int r = 0; r < 16; ++r) {
      const int c = (r & 3) + 8 * (r >> 2);
      if ((h0 >> c) & 1u) sf0[r] = -1e30f;
      if ((h1 >> c) & 1u) sf1[r] = -1e30f;
    }
    float tm = sf0[0];
#pragma unroll
    for (int r = 1; r < 16; ++r) tm = fmaxf(tm, sf0[r]);
#pragma unroll
    for (int r = 0; r < 16; ++r) tm = fmaxf(tm, sf1[r]);

    bool small = __all(tm <= m_run + 8.0f);
    if (!small) {
      float tmx = fmaxf(tm, __shfl_xor(tm, 32, 64));   // rare path only
      float mnew = fmaxf(m_run, tmx);
      float scl = __builtin_amdgcn_exp2f(m_run - mnew);
      m_run = mnew;
      l_run *= scl;
      // reads oacc -> reg dependency forces PV(t-1) completion first: exact
#pragma unroll
      for (int r = 0; r < 16; ++r) {
        float s_ = __shfl(scl, (r & 3) + 8 * (r >> 2) + 4 * hi, 64);
        oacc0[r] *= s_;
        oacc1[r] *= s_;
      }
    }

    float ss = 0.f;
#pragma unroll
    for (int r = 0; r < 16; ++r) {
      sf0[r] = __builtin_amdgcn_exp2f(sf0[r] - m_run);
      sf1[r] = __builtin_amdgcn_exp2f(sf1[r] - m_run);
      ss += sf0[r] + sf1[r];
    }
    l_run += ss;

    // pack P(t) for next iter's PV (native D-layout slots — r9-verified)
#pragma unroll
    for (int m = 0; m < 4; ++m) {
      const int base = (m & 1) * 8;
      s16x8 pa;
#pragma unroll
      for (int e = 0; e < 8; ++e)
        pa[e] = f2bf(m < 2 ? sf0[base + e] : sf1[base + e]);
      pPack[m] = pa;
    }

    // V-reg reads must land before other waves overwrite buf cb (iter t+1)
    asm volatile("s_waitcnt lgkmcnt(0)" ::: "memory");
    __builtin_amdgcn_sched_barrier(0);
    cb = (cb == 2) ? 0 : cb + 1;
  }
#undef STAGE

  // final PV(31)
  __builtin_amdgcn_s_setprio(1);
#pragma unroll
  for (int m = 0; m < 4; ++m) {
    oacc0 = __builtin_amdgcn_mfma_f32_32x32x16_bf16(pPack[m], vA[m], oacc0, 0, 0, 0);
    oacc1 = __builtin_amdgcn_mfma_f32_32x32x16_bf16(pPack[m], vB[m], oacc1, 0, 0, 0);
  }
  __builtin_amdgcn_s_setprio(0);

  // epilogue: merge half-sums, divide (oacc[r]: q'=crow(r,hi), d=ql)
  float l_tot = l_run + __shfl_xor(l_run, 32, 64);
#pragma unroll
  for (int r = 0; r < 16; ++r) {
    int c = (r & 3) + 8 * (r >> 2) + 4 * hi;
    float linv = 1.0f / __shfl(l_tot, c, 64);
    int q_ = q0 + wid * 32 + c;
    size_t base = ((size_t)b * SEQ + q_) * DMODEL + h * DHEAD + ql;
    Ctx[base] = f2bf(oacc0[r] * linv);
    Ctx[base + 32] = f2bf(oacc1[r] * linv);
  }
}

// ---------------------------------------------------------------------------
// Output projection: ctx bf16 @ Wo + bo -> fp32 out.  3-buffer counted-vmcnt
// pipeline, XCD-swizzled (256 = 8 x 32).  grid 256, block 256.
// ---------------------------------------------------------------------------
__global__ __launch_bounds__(256) void proj_out_kernel(
    const short* __restrict__ Ctx, const short* __restrict__ Wot,
    const float* __restrict__ bo, float* __restrict__ Out) {
  __shared__ short As[3][128 * 32];
  __shared__ short Bs[3][128 * 32];
  int wg = blockIdx.x;
  int orig = (wg & 7) * 32 + (wg >> 3);
  int mx = orig >> 3, ny = orig & 7;
  int m0 = mx * 128, n0 = ny * 128;
  int t = threadIdx.x, wid = t >> 6, lane = t & 63;
  int lr = lane & 15, lg = lane >> 4;
  int wr = wid >> 1, wc = wid & 1;
  f32x4 acc[4][4] = {};

  const int gr0 = t >> 2, gc0 = (t & 3) << 3;
  const short* Actx0 = Ctx + (size_t)(m0 + gr0) * DMODEL + gc0;
  const short* Actx1 = Actx0 + (size_t)64 * DMODEL;
  const short* Bwo0 = Wot + (size_t)(n0 + gr0) * DMODEL + gc0;
  const short* Bwo1 = Bwo0 + (size_t)64 * DMODEL;
  const int lofs0 = (t & ~63) << 3, lofs1 = lofs0 + 256 * 8;

#define STAGE_PO(bufi, k0s) {                                                 \
    gload_lds16(Actx0 + (k0s), &As[bufi][0] + lofs0);                         \
    gload_lds16(Actx1 + (k0s), &As[bufi][0] + lofs1);                         \
    gload_lds16(Bwo0 + (k0s), &Bs[bufi][0] + lofs0);                          \
    gload_lds16(Bwo1 + (k0s), &Bs[bufi][0] + lofs1); }

  STAGE_PO(0, 0);
  STAGE_PO(1, 32);

  int cb = 0;
  for (int kt = 0; kt < 32; ++kt) {
    if (kt + 1 < 32) { asm volatile("s_waitcnt vmcnt(4)" ::: "memory"); }
    else             { asm volatile("s_waitcnt vmcnt(0)" ::: "memory"); }
    __builtin_amdgcn_sched_barrier(0);
    __builtin_amdgcn_s_barrier();
    __builtin_amdgcn_sched_barrier(0);
    int st = cb + 2; if (st > 2) st -= 3;
    if (kt + 2 < 32) STAGE_PO(st, (kt + 2) * 32);

    s16x8 afr[4], bfr[4];
#pragma unroll
    for (int mi = 0; mi < 4; ++mi)
      afr[mi] = *(const s16x8*)(&As[cb][0] + (wr * 64 + mi * 16 + lr) * 32 + lg * 8);
#pragma unroll
    for (int ni = 0; ni < 4; ++ni)
      bfr[ni] = *(const s16x8*)(&Bs[cb][0] + (wc * 64 + ni * 16 + lr) * 32 + lg * 8);
    __builtin_amdgcn_s_setprio(1);
#pragma unroll
    for (int mi = 0; mi < 4; ++mi)
#pragma unroll
      for (int ni = 0; ni < 4; ++ni)
        acc[mi][ni] = __builtin_amdgcn_mfma_f32_16x16x32_bf16(
            afr[mi], bfr[ni], acc[mi][ni], 0, 0, 0);
    __builtin_amdgcn_s_setprio(0);
    cb = (cb == 2) ? 0 : cb + 1;
  }
#undef STAGE_PO

#pragma unroll
  for (int mi = 0; mi < 4; ++mi)
#pragma unroll
    for (int ni = 0; ni < 4; ++ni) {
      int n = n0 + wc * 64 + ni * 16 + lr;
      float bv_ = bo[n];
#pragma unroll
      for (int r = 0; r < 4; ++r) {
        int m = m0 + wr * 64 + mi * 16 + lg * 4 + r;
        Out[(size_t)m * DMODEL + n] = acc[mi][ni][r] + bv_;
      }
    }
}

// ---------------------------------------------------------------------------
extern "C" void kernel_launch(void* const* d_in, const int* in_sizes, int n_in,
                              void* d_out, int out_size, void* d_ws, size_t ws_size,
                              hipStream_t stream) {
  const float* key_in   = (const float*)d_in[0];
  const float* value_in = (const float*)d_in[1];
  const float* query_in = (const float*)d_in[2];
  const int*   mask     = (const int*)d_in[3];
  const float* Wq = (const float*)d_in[4];
  const float* bq = (const float*)d_in[5];
  const float* Wk = (const float*)d_in[6];
  const float* bk = (const float*)d_in[7];
  const float* Wv = (const float*)d_in[8];
  const float* bv = (const float*)d_in[9];
  const float* Wo = (const float*)d_in[10];
  const float* bo = (const float*)d_in[11];
  float* out = (float*)d_out;

  short* ws = (short*)d_ws;
  const size_t WSZ   = (size_t)DMODEL * DMODEL;              // 1M elems
  const size_t QKVSZ = (size_t)BATCH * NHEAD * SEQ * DHEAD;  // 4M elems
  short* Wt  = ws;                         // [0, 4M)   4 weights bf16
  short* QKV = ws + 4 * WSZ;               // Q [4M,8M) K [8M,12M) V^T [12M,16M)
  short* Qb  = QKV;
  short* Kb  = QKV + QKVSZ;
  short* VbT = QKV + 2 * QKVSZ;            // [bh][d][s]
  short* Xb  = ws + 4 * WSZ + 3 * QKVSZ;   // [16M, 28M)  bf16 activations
  short* Ctx = Xb;                         // overlays Xb[query] (dead by attn)
  // Mp lives in d_out (1MB << 16MB): written by prep, consumed by attn,
  // fully overwritten by proj_out afterwards (stream-serial, capture-safe).
  unsigned long long* Mp = (unsigned long long*)d_out;

  prep_kernel<<<dim3(8192), 256, 0, stream>>>(
      Wq, Wk, Wv, Wo, Wt, query_in, key_in, value_in, Xb, mask, Mp);
  proj_qkv_kernel<<<dim3(768), 256, 0, stream>>>(Xb, Wt, bq, bk, bv, QKV);
  attn_kernel<<<dim3(512), 256, 0, stream>>>(Qb, Kb, VbT, Mp, Ctx);
  proj_out_kernel<<<dim3(256), 256, 0, stream>>>(Ctx, Wt + 3 * WSZ, bo, out);
}